// Round 8
// baseline (110.176 us; speedup 1.0000x reference)
//
#include <hip/hip_runtime.h>
#include <hip/hip_bf16.h>

typedef unsigned short u16;
typedef unsigned int u32;
typedef __attribute__((ext_vector_type(8))) short bf16x8;
typedef __attribute__((ext_vector_type(4))) float f32x4;
typedef __attribute__((ext_vector_type(4))) int i32x4;

#define N_HEADS 9
#define T_SEQ 2048
#define BATCH 4
#define CDIM 576
#define ROWS (BATCH * T_SEQ) /* 8192 */
#define NBH (BATCH * N_HEADS) /* 36 */
#define PART_SLOT ((size_t)NBH * T_SEQ * 32) /* u16 elements per partial slot */

__device__ __forceinline__ u16 f2bf(float f) {
    u32 u = __float_as_uint(f);
    u32 r = u + 0x7FFFu + ((u >> 16) & 1u);
    return (u16)(r >> 16);
}
__device__ __forceinline__ float bf2f(u16 u) { return __uint_as_float(((u32)u) << 16); }
__device__ __forceinline__ u32 cvt_pk_bf16(float lo, float hi) {
    u32 r;
    asm("v_cvt_pk_bf16_f32 %0, %1, %2" : "=v"(r) : "v"(lo), "v"(hi));
    return r;
}
__device__ __forceinline__ float exp2_raw(float x) {
    float r;
    asm("v_exp_f32 %0, %1" : "=v"(r) : "v"(x));
    return r;
}
__device__ __forceinline__ void gll16(const void* g, void* l) {
    using GP = const __attribute__((address_space(1))) unsigned int*;
    using LP = __attribute__((address_space(3))) unsigned int*;
    __builtin_amdgcn_global_load_lds((GP)g, (LP)l, 16, 0, 0);
}

// ---------------- merged prep: weights + trig tables ----------------
__global__ __launch_bounds__(256) void prep_wt(const float* __restrict__ Wq, const float* __restrict__ Wk,
                                               const float* __restrict__ Wv, const float* __restrict__ Wo,
                                               u16* __restrict__ WcT, u16* __restrict__ WoSubT,
                                               float* __restrict__ cosT, float* __restrict__ sinT) {
    int idx = blockIdx.x * 256 + threadIdx.x;
    if (idx < 576 * 576) {
        int n = idx / 576, k = idx - n * 576;
        float v;
        if (n < 189)      v = Wq[(size_t)k * 576 + (n / 21) * 64 + (n % 21)];
        else if (n < 378) v = Wk[(size_t)k * 189 + (n - 189)];
        else if (n < 567) v = Wv[(size_t)k * 189 + (n - 378)];
        else              v = 0.f;
        WcT[(size_t)n * 576 + k] = f2bf(v);
    }
    if (idx < 576 * 192) {
        int n = idx / 192, k = idx - n * 192;
        float v = 0.f;
        if (k < 189) v = Wo[(size_t)((k / 21) * 64 + (k % 21)) * 576 + n];
        WoSubT[(size_t)n * 192 + k] = f2bf(v);
    }
    if (idx < T_SEQ * 21) {
        int t = idx / 21, d = idx - t * 21;
        int i = (d < 11) ? d : d - 11;
        float e = (2.0f * (float)i) / 21.0f;
        float invf = exp2f(-e * 13.287712379549449f); // 10000^-e
        float ang = (float)t * invf;
        cosT[idx] = cosf(ang);
        sinT[idx] = sinf(ang);
    }
}

// ---------------- bf16 MFMA GEMM: C[M,N] = A[M,K] * BT[N,K]^T ----------------
// 128x64 tile, 4 waves. Grid: (N/64, M/128) — n fastest so consecutive blocks share A panel (L2).
// AF32: A is f32, converted to bf16 in-register during staging. Register prefetch of next k-tile.

template <int AF32, int OUTF32>
__global__ __launch_bounds__(256) void gemm_mfma(const void* __restrict__ Av, const u16* __restrict__ BT,
                                                 void* __restrict__ Cout, int K, int lda, int ldbt, int ldc) {
    __shared__ u16 As[128][32];
    __shared__ u16 Bs[64][32];
    const int tid = threadIdx.x;
    const int lane = tid & 63, w = tid >> 6;
    const int m0 = blockIdx.y * 128, n0 = blockIdx.x * 64;
    const int k15 = lane & 15, g = lane >> 4;

    const int arow = tid >> 1;          // 0..127
    const int ac0 = (tid & 1) * 2;      // chunks ac0, ac0+1
    const int brow = tid >> 2, bc = tid & 3;

    f32x4 zero = {0.f, 0.f, 0.f, 0.f};
    f32x4 acc[2][4];
#pragma unroll
    for (int hf = 0; hf < 2; hf++)
#pragma unroll
        for (int n = 0; n < 4; n++) acc[hf][n] = zero;

    const float* Af = (const float*)Av;
    const u16*   Ab = (const u16*)Av;

    float4 af0, af1, af2, af3;
    i32x4 av0, av1;
    if (AF32) {
        const float* ap = &Af[(size_t)(m0 + arow) * lda + ac0 * 8];
        af0 = *(const float4*)&ap[0];
        af1 = *(const float4*)&ap[4];
        af2 = *(const float4*)&ap[8];
        af3 = *(const float4*)&ap[12];
    } else {
        av0 = *(const i32x4*)&Ab[(size_t)(m0 + arow) * lda + ac0 * 8];
        av1 = *(const i32x4*)&Ab[(size_t)(m0 + arow) * lda + (ac0 + 1) * 8];
    }
    i32x4 bv = *(const i32x4*)&BT[(size_t)(n0 + brow) * ldbt + bc * 8];

    for (int k0 = 0; k0 < K; k0 += 32) {
        __syncthreads();
        if (AF32) {
            i32x4 w0, w1;
            w0[0] = (int)cvt_pk_bf16(af0.x, af0.y); w0[1] = (int)cvt_pk_bf16(af0.z, af0.w);
            w0[2] = (int)cvt_pk_bf16(af1.x, af1.y); w0[3] = (int)cvt_pk_bf16(af1.z, af1.w);
            w1[0] = (int)cvt_pk_bf16(af2.x, af2.y); w1[1] = (int)cvt_pk_bf16(af2.z, af2.w);
            w1[2] = (int)cvt_pk_bf16(af3.x, af3.y); w1[3] = (int)cvt_pk_bf16(af3.z, af3.w);
            *(i32x4*)&As[arow][(ac0 ^ (arow & 3)) * 8] = w0;
            *(i32x4*)&As[arow][((ac0 + 1) ^ (arow & 3)) * 8] = w1;
        } else {
            *(i32x4*)&As[arow][(ac0 ^ (arow & 3)) * 8] = av0;
            *(i32x4*)&As[arow][((ac0 + 1) ^ (arow & 3)) * 8] = av1;
        }
        *(i32x4*)&Bs[brow][(bc ^ (brow & 3)) * 8] = bv;
        __syncthreads();
        int k1 = k0 + 32;
        if (k1 < K) {
            if (AF32) {
                const float* ap = &Af[(size_t)(m0 + arow) * lda + k1 + ac0 * 8];
                af0 = *(const float4*)&ap[0];
                af1 = *(const float4*)&ap[4];
                af2 = *(const float4*)&ap[8];
                af3 = *(const float4*)&ap[12];
            } else {
                av0 = *(const i32x4*)&Ab[(size_t)(m0 + arow) * lda + k1 + ac0 * 8];
                av1 = *(const i32x4*)&Ab[(size_t)(m0 + arow) * lda + k1 + (ac0 + 1) * 8];
            }
            bv = *(const i32x4*)&BT[(size_t)(n0 + brow) * ldbt + k1 + bc * 8];
        }
        const int ar0 = w * 32 + k15;
        bf16x8 a0 = *(const bf16x8*)&As[ar0][(g ^ (ar0 & 3)) * 8];
        bf16x8 a1 = *(const bf16x8*)&As[ar0 + 16][(g ^ (ar0 & 3)) * 8];
#pragma unroll
        for (int n = 0; n < 4; n++) {
            int br = n * 16 + k15;
            bf16x8 b = *(const bf16x8*)&Bs[br][(g ^ (br & 3)) * 8];
            acc[0][n] = __builtin_amdgcn_mfma_f32_16x16x32_bf16(a0, b, acc[0][n], 0, 0, 0);
            acc[1][n] = __builtin_amdgcn_mfma_f32_16x16x32_bf16(a1, b, acc[1][n], 0, 0, 0);
        }
    }
#pragma unroll
    for (int hf = 0; hf < 2; hf++)
#pragma unroll
        for (int n = 0; n < 4; n++)
#pragma unroll
            for (int i = 0; i < 4; i++) {
                int row = m0 + w * 32 + hf * 16 + g * 4 + i;
                int col = n0 + n * 16 + k15;
                float v = acc[hf][n][i];
                if (OUTF32) ((float*)Cout)[(size_t)row * ldc + col] = v;
                else        ((u16*)Cout)[(size_t)row * ldc + col] = f2bf(v);
            }
}

// ---------------- repack: rope + pad to d=32, gll-ready swizzled unit-major layouts ----------------
// Qp[bh][t][32] (roped, scaled). Kp[bh][unit 16][quad-swizzled 128x32]: quad(k,c) = k*4 + (c ^ ((k>>2)&3)).
// Vp[bh][unit 16][quad-swizzled 32x128]: quad(d,c) = d*16 + (c ^ (d&7)); rows d=21..30 zero, d=31 ones.

__global__ __launch_bounds__(256) void repack_qk(const u16* __restrict__ qkv,
                                                 const float* __restrict__ cosT,
                                                 const float* __restrict__ sinT,
                                                 u16* __restrict__ Qp, u16* __restrict__ Kp) {
    int gid = blockIdx.x * 256 + threadIdx.x; // 36*2048*4
    int c = gid & 3;
    int t = (gid >> 2) & 2047;
    int bh = gid >> 13;
    int b = bh / N_HEADS, h = bh - b * N_HEADS;
    const u16* qrow = qkv + (size_t)(b * T_SEQ + t) * CDIM + h * 21;
    const u16* krow = qrow + 189;
    const float* cr = cosT + t * 21;
    const float* sr = sinT + t * 21;
    u32 wq[4] = {0, 0, 0, 0}, wk[4] = {0, 0, 0, 0};
    const float sc = 0.18033688011112042f; // 0.125 * log2(e)
#pragma unroll
    for (int j = 0; j < 8; j++) {
        int d = c * 8 + j;
        float vq = 0.f, vk = 0.f;
        if (d < 21) {
            int pd = (d < 11) ? d + 10 : d - 11;
            float cc = cr[d], ss = sr[d];
            float qv = bf2f(qrow[d]), qp = bf2f(qrow[pd]);
            float kv = bf2f(krow[d]), kp = bf2f(krow[pd]);
            float rq = (d < 11) ? -qp : qp;
            float rk = (d < 11) ? -kp : kp;
            vq = (qv * cc + rq * ss) * sc;
            vk = kv * cc + rk * ss;
        }
        wq[j >> 1] |= (u32)f2bf(vq) << ((j & 1) * 16);
        wk[j >> 1] |= (u32)f2bf(vk) << ((j & 1) * 16);
    }
    i32x4 q4; q4[0] = (int)wq[0]; q4[1] = (int)wq[1]; q4[2] = (int)wq[2]; q4[3] = (int)wq[3];
    i32x4 k4; k4[0] = (int)wk[0]; k4[1] = (int)wk[1]; k4[2] = (int)wk[2]; k4[3] = (int)wk[3];
    *(i32x4*)&Qp[((size_t)bh * T_SEQ + t) * 32 + c * 8] = q4;
    int k = t & 127, u = t >> 7;
    int ql = k * 4 + (c ^ ((k >> 2) & 3));
    *(i32x4*)&Kp[(size_t)bh * 65536 + (size_t)u * 4096 + ql * 8] = k4;
}

// V transpose via LDS; block = (256 t = 2 units, bh).
__global__ __launch_bounds__(256) void repack_v(const u16* __restrict__ qkv, u16* __restrict__ Vp) {
    __shared__ u16 Vs[256][26];
    const int tid = threadIdx.x;
    const int bh = blockIdx.y;
    const int b = bh / N_HEADS, h = bh - b * N_HEADS;
    const int t0 = blockIdx.x * 256;

    const u16* src = qkv + (size_t)(b * T_SEQ + t0 + tid) * CDIM + 378 + h * 21;
#pragma unroll
    for (int d = 0; d < 21; d++) Vs[tid][d] = src[d];
    __syncthreads();

    const int d = tid >> 3, tc = tid & 7;
    u32 wv[16];
#pragma unroll
    for (int j = 0; j < 32; j += 2) {
        u16 lo, hi;
        if (d < 21)      { lo = Vs[tc * 32 + j][d]; hi = Vs[tc * 32 + j + 1][d]; }
        else if (d == 31){ lo = 0x3F80; hi = 0x3F80; }
        else             { lo = 0; hi = 0; }
        wv[j >> 1] = (u32)lo | ((u32)hi << 16);
    }
    const int unit = blockIdx.x * 2 + (tc >> 2);
    u16* dstU = Vp + (size_t)bh * 65536 + (size_t)unit * 4096;
#pragma unroll
    for (int m = 0; m < 4; m++) {
        int c = (tc & 3) * 4 + m;
        int ql = d * 16 + (c ^ (d & 7));
        i32x4 v4; v4[0] = (int)wv[m * 4]; v4[1] = (int)wv[m * 4 + 1]; v4[2] = (int)wv[m * 4 + 2]; v4[3] = (int)wv[m * 4 + 3];
        *(i32x4*)&dstU[ql * 8] = v4;
    }
}

// ---------------- split-K MFMA flash attention ----------------
// Fixed-base softmax (bounded scores) => linear in keys => split-K partials.
// Balanced chunks: nc(qt) = qt/8+1 chunks of <=4 units (128 keys each). 80 chunks/bh, heavy-first.
// K/V staged by global_load_lds (width 16) into double-buffered LDS; counted vmcnt(4) keeps
// next-unit loads in flight across barriers. LDS reads <=2-way bank aliasing by construction.

__global__ __launch_bounds__(256) void attn_mfma(const u16* __restrict__ Qp,
                                                 const u16* __restrict__ Kp,
                                                 const u16* __restrict__ Vp,
                                                 u16* __restrict__ Ybuf,
                                                 u16* __restrict__ Part) {
    __shared__ u16 KsB[2][4096];   // 2 x 8KB: [k 0..127][32d quad-swizzled]
    __shared__ u16 VsB[2][4096];   // 2 x 8KB: [d 0..31][128k quad-swizzled]
    __shared__ u16 Pt[4][16][72];  // per-wave P^T round trip
    const int tid = threadIdx.x;
    const int lane = tid & 63, w = tid >> 6;
    const int bh = blockIdx.y;
    const int b = bh / N_HEADS, h = bh - b * N_HEADS;
    const int k15 = lane & 15, g = lane >> 4;

    int bx = blockIdx.x, qt, ci;
    if (bx < 32)      { qt = 31 - (bx >> 2); ci = bx & 3; }
    else if (bx < 56) { int r = bx - 32; int q3 = r / 3; qt = 23 - q3; ci = r - q3 * 3; }
    else if (bx < 72) { int r = bx - 56; qt = 15 - (r >> 1); ci = r & 1; }
    else              { qt = 79 - bx; ci = 0; }
    const int q0 = qt * 64;
    const int n128 = (qt + 2) >> 1;       // units covering keys 0..q0+63
    const int nc = (qt >> 3) + 1;         // chunks for this qt
    const int u_begin = (ci * n128) / nc;
    const int u_end = ((ci + 1) * n128) / nc;

    const char* KgU = (const char*)Kp + (size_t)bh * 131072;
    const char* VgU = (const char*)Vp + (size_t)bh * 131072;
    char* Kl0 = (char*)&KsB[0][0];
    char* Vl0 = (char*)&VsB[0][0];

    // Q fragment first (oldest vmcnt entry)
    bf16x8 qf = *(const bf16x8*)&Qp[(((size_t)bh << 11) + q0 + w * 16 + k15) * 32 + g * 8];

    auto stage = [&](int u, int buf) {
        size_t go = (size_t)u * 8192 + (size_t)(w * 2048 + lane * 16);
        char* kl = Kl0 + buf * 8192 + w * 2048;
        char* vl = Vl0 + buf * 8192 + w * 2048;
        gll16(KgU + go, kl);
        gll16(KgU + go + 1024, kl + 1024);
        gll16(VgU + go, vl);
        gll16(VgU + go + 1024, vl + 1024);
    };

    f32x4 y0 = {0.f, 0.f, 0.f, 0.f}, y1 = {0.f, 0.f, 0.f, 0.f};
    const int qloc = w * 16 + k15;
    const int kb  = k15 * 64 + ((g ^ ((k15 >> 2) & 3)) * 16);       // K lane base (bytes)
    const int vb0 = k15 * 256 + (((0 * 4 + g) ^ (k15 & 7)) * 16);   // V kh=0 base (bytes)
    const int vb1 = k15 * 256 + (((1 * 4 + g) ^ (k15 & 7)) * 16);   // V kh=1 base (bytes)

    stage(u_begin, 0);
    int cur = 0;
    for (int u = u_begin; u < u_end; ++u) {
        __builtin_amdgcn_s_barrier();           // all waves done reading buf[cur^1]
        asm volatile("" ::: "memory");
        if (u + 1 < u_end) {
            stage(u + 1, cur ^ 1);
            asm volatile("s_waitcnt vmcnt(4)" ::: "memory");  // my buf[cur] loads landed
        } else {
            asm volatile("s_waitcnt vmcnt(0)" ::: "memory");
        }
        __builtin_amdgcn_s_barrier();           // everyone's buf[cur] landed
        asm volatile("" ::: "memory");

        const char* Kb = Kl0 + cur * 8192;
        const char* Vb = Vl0 + cur * 8192;
#pragma unroll
        for (int sub = 0; sub < 2; ++sub) {
            const int kt64 = u * 2 + sub;
            if (kt64 <= qt) {
                // QK^T (swapped): S^T frag f: rows = keys f*16+g*4+i, col = q = k15
                f32x4 s[4];
#pragma unroll
                for (int f = 0; f < 4; f++) {
                    bf16x8 kf = *(const bf16x8*)(Kb + sub * 4096 + f * 1024 + kb);
                    f32x4 z = {0.f, 0.f, 0.f, 0.f};
                    s[f] = __builtin_amdgcn_mfma_f32_16x16x32_bf16(kf, qf, z, 0, 0, 0);
                }
                if (kt64 == qt) { // diagonal: mask key_local > w*16 + q_local
#pragma unroll
                    for (int f = 0; f < 4; f++)
#pragma unroll
                        for (int i = 0; i < 4; i++)
                            if (f * 16 + g * 4 + i > qloc) s[f][i] = -16384.f;
                }
                // P = exp2(S), pack bf16, write P^T
#pragma unroll
                for (int f = 0; f < 4; f++) {
                    u32 lo = cvt_pk_bf16(exp2_raw(s[f][0]), exp2_raw(s[f][1]));
                    u32 hi = cvt_pk_bf16(exp2_raw(s[f][2]), exp2_raw(s[f][3]));
                    uint2 pk; pk.x = lo; pk.y = hi;
                    *(uint2*)&Pt[w][k15][f * 16 + g * 4] = pk;
                }
                asm volatile("" ::: "memory");
                // PV: A[m=q][k=key] from Pt, B[n=d][k=key] from swizzled Vt
#pragma unroll
                for (int kh = 0; kh < 2; kh++) {
                    const int vb = kh ? vb1 : vb0;
                    bf16x8 pa = *(const bf16x8*)&Pt[w][k15][kh * 32 + g * 8];
                    bf16x8 v0 = *(const bf16x8*)(Vb + sub * 128 + vb);
                    bf16x8 v1 = *(const bf16x8*)(Vb + sub * 128 + vb + 4096);
                    y0 = __builtin_amdgcn_mfma_f32_16x16x32_bf16(pa, v0, y0, 0, 0, 0);
                    y1 = __builtin_amdgcn_mfma_f32_16x16x32_bf16(pa, v1, y1, 0, 0, 0);
                }
                asm volatile("" ::: "memory");
            }
        }
        cur ^= 1;
    }

    if (nc == 1) { // single chunk: normalize by l (= y1 col 15 = ones-column) and write
#pragma unroll
        for (int i = 0; i < 4; i++) {
            float li = __shfl(y1[i], (lane & 48) + 15);
            float inv = 1.0f / li;
            int rowY = b * T_SEQ + q0 + w * 16 + g * 4 + i;
            u16* yr = &Ybuf[(size_t)rowY * 192 + h * 21];
            yr[k15] = f2bf(y0[i] * inv);
            if (k15 < 5) yr[16 + k15] = f2bf(y1[i] * inv);
        }
    } else { // bf16 partials (denominator at d=31)
#pragma unroll
        for (int i = 0; i < 4; i++) {
            size_t pb = (size_t)ci * PART_SLOT +
                        (((size_t)bh << 11) + q0 + w * 16 + g * 4 + i) * 32;
            Part[pb + k15] = f2bf(y0[i]);
            Part[pb + 16 + k15] = f2bf(y1[i]);
        }
    }
}

// combine nc partial slots for rows t >= 512, normalize, write Ybuf
__global__ __launch_bounds__(256) void attn_reduce(const u16* __restrict__ Part, u16* __restrict__ Ybuf) {
    int gid = blockIdx.x * 256 + threadIdx.x; // 36 * 1536 * 32
    int d = gid & 31;
    int rest = gid >> 5;
    int t = 512 + (rest % 1536);
    int bh = rest / 1536;
    int b = bh / N_HEADS, h = bh - b * N_HEADS;
    int qt = t >> 6;
    int nc = (qt >> 3) + 1;
    size_t base = (((size_t)bh << 11) + t) * 32;
    float l = 0.f, v = 0.f;
    for (int ci = 0; ci < nc; ci++) {
        l += bf2f(Part[(size_t)ci * PART_SLOT + base + 31]);
        if (d < 21) v += bf2f(Part[(size_t)ci * PART_SLOT + base + d]);
    }
    if (d < 21) Ybuf[(size_t)(b * T_SEQ + t) * 192 + h * 21 + d] = f2bf(v / l);
}

// ---------------- launch ----------------

extern "C" void kernel_launch(void* const* d_in, const int* in_sizes, int n_in,
                              void* d_out, int out_size, void* d_ws, size_t ws_size,
                              hipStream_t stream) {
    const float* x  = (const float*)d_in[0];
    const float* Wq = (const float*)d_in[1];
    const float* Wk = (const float*)d_in[2];
    const float* Wv = (const float*)d_in[3];
    const float* Wo = (const float*)d_in[4];
    float* out = (float*)d_out;

    char* p = (char*)d_ws;
    auto alloc = [&](size_t bytes) { char* r = p; p += (bytes + 255) & ~(size_t)255; return r; };
    u16*   QpKp   = (u16*)alloc((size_t)ROWS * CDIM * 2);   // Qp | Kp
    u16*   qkv    = (u16*)alloc((size_t)ROWS * CDIM * 2);
    u16*   WcT    = (u16*)alloc((size_t)576 * 576 * 2);
    u16*   WoSubT = (u16*)alloc((size_t)576 * 192 * 2);
    float* cosT   = (float*)alloc((size_t)T_SEQ * 21 * 4);
    float* sinT   = (float*)alloc((size_t)T_SEQ * 21 * 4);
    u16*   Vp     = (u16*)alloc((size_t)NBH * 16 * 4096 * 2);
    u16*   Ybuf   = (u16*)alloc((size_t)ROWS * 192 * 2);
    u16*   Part   = (u16*)alloc((size_t)4 * PART_SLOT * 2);

    u16* Qp = QpKp;
    u16* Kp = QpKp + (size_t)NBH * T_SEQ * 32;

    prep_wt<<<dim3((576 * 576 + 255) / 256), dim3(256), 0, stream>>>(Wq, Wk, Wv, Wo, WcT, WoSubT, cosT, sinT);

    // QKV projection: [8192,576(f32)] x [576,567(->576)] — f32 A converted in staging
    gemm_mfma<1, 0><<<dim3(576 / 64, ROWS / 128), dim3(256), 0, stream>>>((const void*)x, WcT, (void*)qkv, 576, 576, 576, 576);

    // rope + repack into gll-ready swizzled layouts
    repack_qk<<<dim3(NBH * T_SEQ * 4 / 256), dim3(256), 0, stream>>>(qkv, cosT, sinT, Qp, Kp);
    repack_v<<<dim3(T_SEQ / 256, NBH), dim3(256), 0, stream>>>(qkv, Vp);

    // balanced split-K MFMA flash attention + combine
    attn_mfma<<<dim3(80, NBH), dim3(256), 0, stream>>>(Qp, Kp, Vp, Ybuf, Part);
    attn_reduce<<<dim3(NBH * 1536 * 32 / 256), dim3(256), 0, stream>>>(Part, Ybuf);

    // output GEMM: [8192,192] x [192,576]
    gemm_mfma<0, 1><<<dim3(576 / 64, ROWS / 128), dim3(256), 0, stream>>>((const void*)Ybuf, WoSubT, (void*)out, 192, 192, 192, 576);
}

// Round 10
// 92.399 us; speedup vs baseline: 1.1924x; 1.1924x over previous
//
#include <hip/hip_runtime.h>
#include <hip/hip_bf16.h>

typedef unsigned short u16;
typedef unsigned int u32;
typedef __attribute__((ext_vector_type(8))) short bf16x8;
typedef __attribute__((ext_vector_type(4))) float f32x4;
typedef __attribute__((ext_vector_type(4))) int i32x4;

#define N_HEADS 9
#define T_SEQ 2048
#define BATCH 4
#define CDIM 576
#define ROWS (BATCH * T_SEQ) /* 8192 */
#define NBH (BATCH * N_HEADS) /* 36 */
#define PART_SLOT ((size_t)NBH * T_SEQ * 32) /* u16 elements per partial slot */

__device__ __forceinline__ u16 f2bf(float f) {
    u32 u = __float_as_uint(f);
    u32 r = u + 0x7FFFu + ((u >> 16) & 1u);
    return (u16)(r >> 16);
}
__device__ __forceinline__ float bf2f(u16 u) { return __uint_as_float(((u32)u) << 16); }
__device__ __forceinline__ u32 cvt_pk_bf16(float lo, float hi) {
    u32 r;
    asm("v_cvt_pk_bf16_f32 %0, %1, %2" : "=v"(r) : "v"(lo), "v"(hi));
    return r;
}
__device__ __forceinline__ float exp2_raw(float x) {
    float r;
    asm("v_exp_f32 %0, %1" : "=v"(r) : "v"(x));
    return r;
}

// ---------------- merged prep: weights + trig tables ----------------
__global__ __launch_bounds__(256) void prep_wt(const float* __restrict__ Wq, const float* __restrict__ Wk,
                                               const float* __restrict__ Wv, const float* __restrict__ Wo,
                                               u16* __restrict__ WcT, u16* __restrict__ WoSubT,
                                               float* __restrict__ cosT, float* __restrict__ sinT) {
    int idx = blockIdx.x * 256 + threadIdx.x;
    if (idx < 576 * 576) {
        int n = idx / 576, k = idx - n * 576;
        float v;
        if (n < 189)      v = Wq[(size_t)k * 576 + (n / 21) * 64 + (n % 21)];
        else if (n < 378) v = Wk[(size_t)k * 189 + (n - 189)];
        else if (n < 567) v = Wv[(size_t)k * 189 + (n - 378)];
        else              v = 0.f;
        WcT[(size_t)n * 576 + k] = f2bf(v);
    }
    if (idx < 576 * 192) {
        int n = idx / 192, k = idx - n * 192;
        float v = 0.f;
        if (k < 189) v = Wo[(size_t)((k / 21) * 64 + (k % 21)) * 576 + n];
        WoSubT[(size_t)n * 192 + k] = f2bf(v);
    }
    if (idx < T_SEQ * 21) {
        int t = idx / 21, d = idx - t * 21;
        int i = (d < 11) ? d : d - 11;
        float e = (2.0f * (float)i) / 21.0f;
        float invf = exp2f(-e * 13.287712379549449f); // 10000^-e
        float ang = (float)t * invf;
        cosT[idx] = cosf(ang);
        sinT[idx] = sinf(ang);
    }
}

// ---------------- bf16 MFMA GEMM: C[M,N] = A[M,K] * BT[N,K]^T ----------------
// 128x64 tile, 4 waves. 1-D grid, m = bx&63, n = bx>>6: blocks sharing an A panel (same m,
// different n) are 64 apart in dispatch index ≡ same (mod 8) -> same XCD L2 -> A fetched once.
// AF32: A is f32, converted to bf16 in-register during staging. Register prefetch of next k-tile.

template <int AF32, int OUTF32>
__global__ __launch_bounds__(256) void gemm_mfma(const void* __restrict__ Av, const u16* __restrict__ BT,
                                                 void* __restrict__ Cout, int K, int lda, int ldbt, int ldc) {
    __shared__ u16 As[128][32];
    __shared__ u16 Bs[64][32];
    const int tid = threadIdx.x;
    const int lane = tid & 63, w = tid >> 6;
    const int m0 = (blockIdx.x & 63) * 128, n0 = (blockIdx.x >> 6) * 64;
    const int k15 = lane & 15, g = lane >> 4;

    const int arow = tid >> 1;          // 0..127
    const int ac0 = (tid & 1) * 2;      // chunks ac0, ac0+1
    const int brow = tid >> 2, bc = tid & 3;

    f32x4 zero = {0.f, 0.f, 0.f, 0.f};
    f32x4 acc[2][4];
#pragma unroll
    for (int hf = 0; hf < 2; hf++)
#pragma unroll
        for (int n = 0; n < 4; n++) acc[hf][n] = zero;

    const float* Af = (const float*)Av;
    const u16*   Ab = (const u16*)Av;

    float4 af0, af1, af2, af3;
    i32x4 av0, av1;
    if (AF32) {
        const float* ap = &Af[(size_t)(m0 + arow) * lda + ac0 * 8];
        af0 = *(const float4*)&ap[0];
        af1 = *(const float4*)&ap[4];
        af2 = *(const float4*)&ap[8];
        af3 = *(const float4*)&ap[12];
    } else {
        av0 = *(const i32x4*)&Ab[(size_t)(m0 + arow) * lda + ac0 * 8];
        av1 = *(const i32x4*)&Ab[(size_t)(m0 + arow) * lda + (ac0 + 1) * 8];
    }
    i32x4 bv = *(const i32x4*)&BT[(size_t)(n0 + brow) * ldbt + bc * 8];

    for (int k0 = 0; k0 < K; k0 += 32) {
        __syncthreads();
        if (AF32) {
            i32x4 w0, w1;
            w0[0] = (int)cvt_pk_bf16(af0.x, af0.y); w0[1] = (int)cvt_pk_bf16(af0.z, af0.w);
            w0[2] = (int)cvt_pk_bf16(af1.x, af1.y); w0[3] = (int)cvt_pk_bf16(af1.z, af1.w);
            w1[0] = (int)cvt_pk_bf16(af2.x, af2.y); w1[1] = (int)cvt_pk_bf16(af2.z, af2.w);
            w1[2] = (int)cvt_pk_bf16(af3.x, af3.y); w1[3] = (int)cvt_pk_bf16(af3.z, af3.w);
            *(i32x4*)&As[arow][(ac0 ^ (arow & 3)) * 8] = w0;
            *(i32x4*)&As[arow][((ac0 + 1) ^ (arow & 3)) * 8] = w1;
        } else {
            *(i32x4*)&As[arow][(ac0 ^ (arow & 3)) * 8] = av0;
            *(i32x4*)&As[arow][((ac0 + 1) ^ (arow & 3)) * 8] = av1;
        }
        *(i32x4*)&Bs[brow][(bc ^ (brow & 3)) * 8] = bv;
        __syncthreads();
        int k1 = k0 + 32;
        if (k1 < K) {
            if (AF32) {
                const float* ap = &Af[(size_t)(m0 + arow) * lda + k1 + ac0 * 8];
                af0 = *(const float4*)&ap[0];
                af1 = *(const float4*)&ap[4];
                af2 = *(const float4*)&ap[8];
                af3 = *(const float4*)&ap[12];
            } else {
                av0 = *(const i32x4*)&Ab[(size_t)(m0 + arow) * lda + k1 + ac0 * 8];
                av1 = *(const i32x4*)&Ab[(size_t)(m0 + arow) * lda + k1 + (ac0 + 1) * 8];
            }
            bv = *(const i32x4*)&BT[(size_t)(n0 + brow) * ldbt + k1 + bc * 8];
        }
        const int ar0 = w * 32 + k15;
        bf16x8 a0 = *(const bf16x8*)&As[ar0][(g ^ (ar0 & 3)) * 8];
        bf16x8 a1 = *(const bf16x8*)&As[ar0 + 16][(g ^ (ar0 & 3)) * 8];
#pragma unroll
        for (int n = 0; n < 4; n++) {
            int br = n * 16 + k15;
            bf16x8 b = *(const bf16x8*)&Bs[br][(g ^ (br & 3)) * 8];
            acc[0][n] = __builtin_amdgcn_mfma_f32_16x16x32_bf16(a0, b, acc[0][n], 0, 0, 0);
            acc[1][n] = __builtin_amdgcn_mfma_f32_16x16x32_bf16(a1, b, acc[1][n], 0, 0, 0);
        }
    }
#pragma unroll
    for (int hf = 0; hf < 2; hf++)
#pragma unroll
        for (int n = 0; n < 4; n++)
#pragma unroll
            for (int i = 0; i < 4; i++) {
                int row = m0 + w * 32 + hf * 16 + g * 4 + i;
                int col = n0 + n * 16 + k15;
                float v = acc[hf][n][i];
                if (OUTF32) ((float*)Cout)[(size_t)row * ldc + col] = v;
                else        ((u16*)Cout)[(size_t)row * ldc + col] = f2bf(v);
            }
}

// ---------------- merged repack: rope Q/K + V transpose, per-head layouts ----------------
// Qp[bh][t][32] (roped, scaled by 0.125*log2e), Kp[bh][t][32] (roped),
// Vp[bh][32][2048] d-major (rows 21..30 zero, row 31 = 1.0 ones/denominator column).

__global__ __launch_bounds__(256) void repack_qkv(const u16* __restrict__ qkv,
                                                  const float* __restrict__ cosT,
                                                  const float* __restrict__ sinT,
                                                  u16* __restrict__ Qp, u16* __restrict__ Kp,
                                                  u16* __restrict__ Vp) {
    __shared__ u16 Vs[64][26];
    const int tid = threadIdx.x;
    const int bh = blockIdx.y;
    const int b = bh / N_HEADS, h = bh - b * N_HEADS;
    const int t0 = blockIdx.x * 64;
    const int r = tid >> 2, c = tid & 3;
    const int t = t0 + r;

    const u16* qrow = qkv + (size_t)(b * T_SEQ + t) * CDIM + h * 21;
    const u16* krow = qrow + 189;
    const u16* vrow = krow + 189;

    // V rows into LDS (d ranges per c: 0-5, 6-11, 12-17, 18-20)
    for (int d = c * 6; d < c * 6 + 6 && d < 21; ++d) Vs[r][d] = vrow[d];

    // rope Q/K for d = c*8 .. c*8+7
    const float* cr = cosT + t * 21;
    const float* sr = sinT + t * 21;
    u32 wq[4] = {0, 0, 0, 0}, wk[4] = {0, 0, 0, 0};
    const float sc = 0.18033688011112042f; // 0.125 * log2(e)
#pragma unroll
    for (int j = 0; j < 8; j++) {
        int d = c * 8 + j;
        float vq = 0.f, vk = 0.f;
        if (d < 21) {
            int pd = (d < 11) ? d + 10 : d - 11;
            float cc = cr[d], ss = sr[d];
            float qv = bf2f(qrow[d]), qp = bf2f(qrow[pd]);
            float kv = bf2f(krow[d]), kp = bf2f(krow[pd]);
            float rq = (d < 11) ? -qp : qp;
            float rk = (d < 11) ? -kp : kp;
            vq = (qv * cc + rq * ss) * sc;
            vk = kv * cc + rk * ss;
        }
        wq[j >> 1] |= (u32)f2bf(vq) << ((j & 1) * 16);
        wk[j >> 1] |= (u32)f2bf(vk) << ((j & 1) * 16);
    }
    size_t obase = ((size_t)bh * T_SEQ + t) * 32 + c * 8;
    i32x4 q4; q4[0] = (int)wq[0]; q4[1] = (int)wq[1]; q4[2] = (int)wq[2]; q4[3] = (int)wq[3];
    i32x4 k4; k4[0] = (int)wk[0]; k4[1] = (int)wk[1]; k4[2] = (int)wk[2]; k4[3] = (int)wk[3];
    *(i32x4*)&Qp[obase] = q4;
    *(i32x4*)&Kp[obase] = k4;

    __syncthreads();

    // phase B: d-major transpose, 8 keys (16B) per thread
    const int d = tid >> 3, tc = tid & 7;
    u32 wv[4];
#pragma unroll
    for (int j = 0; j < 4; j++) {
        u16 lo, hi;
        if (d < 21)      { lo = Vs[tc * 8 + j * 2][d]; hi = Vs[tc * 8 + j * 2 + 1][d]; }
        else if (d == 31){ lo = 0x3F80; hi = 0x3F80; }
        else             { lo = 0; hi = 0; }
        wv[j] = (u32)lo | ((u32)hi << 16);
    }
    i32x4 v4; v4[0] = (int)wv[0]; v4[1] = (int)wv[1]; v4[2] = (int)wv[2]; v4[3] = (int)wv[3];
    *(i32x4*)&Vp[((size_t)bh * 32 + d) * T_SEQ + t0 + tc * 8] = v4;
}

// ---------------- split-K MFMA flash attention (reg-staged double buffer, balanced split) ----------------
// Fixed-base softmax (bounded scores) => linear in keys => split-K partials.
// nc(qt) = qt/8+1 chunks of <=4 units (128 keys each); 80 chunks/bh, heavy-first.

__global__ __launch_bounds__(256) void attn_mfma(const u16* __restrict__ Qp,
                                                 const u16* __restrict__ Kp,
                                                 const u16* __restrict__ Vp,
                                                 u16* __restrict__ Ybuf,
                                                 u16* __restrict__ Part) {
    __shared__ u16 Ks[128][40];    // 80B rows (5 quads)
    __shared__ u16 Vt[32][136];    // 272B rows (17 quads)
    __shared__ u16 Pt[4][16][72];  // 144B rows (9 quads)
    const int tid = threadIdx.x;
    const int lane = tid & 63, w = tid >> 6;
    const int bh = blockIdx.y;
    const int b = bh / N_HEADS, h = bh - b * N_HEADS;
    const int k15 = lane & 15, g = lane >> 4;

    int bx = blockIdx.x, qt, ci;
    if (bx < 32)      { qt = 31 - (bx >> 2); ci = bx & 3; }                    // nc=4
    else if (bx < 56) { int r = bx - 32; int q3 = r / 3; qt = 23 - q3; ci = r - q3 * 3; } // nc=3
    else if (bx < 72) { int r = bx - 56; qt = 15 - (r >> 1); ci = r & 1; }     // nc=2
    else              { qt = 79 - bx; ci = 0; }                                 // nc=1
    const int q0 = qt * 64;
    const int n128 = (qt + 2) >> 1;       // 128-key units covering keys 0..q0+63
    const int nc = (qt >> 3) + 1;
    const int u_begin = (ci * n128) / nc;
    const int u_end = ((ci + 1) * n128) / nc;

    // per-thread staging source pointers
    const u16* Kg = Kp + (((size_t)bh << 11) * 32) + (tid >> 1) * 32 + (tid & 1) * 16;
    const u16* Vg = Vp + (size_t)bh * 32 * T_SEQ + (size_t)(tid >> 3) * T_SEQ + (tid & 7) * 16;
    const int krow = tid >> 1, kcc = (tid & 1) * 16;
    const int vrow = tid >> 3, vcc = (tid & 7) * 16;

    // Q B-fragment held in regs: B[n=q][k=d]
    bf16x8 qf = *(const bf16x8*)&Qp[(((size_t)bh << 11) + q0 + w * 16 + k15) * 32 + g * 8];

    f32x4 y0 = {0.f, 0.f, 0.f, 0.f}, y1 = {0.f, 0.f, 0.f, 0.f};
    const int qloc = w * 16 + k15;

    // prologue loads (unit u_begin)
    u32 ko = (u32)u_begin * 4096u;  // u16 elems per unit in Kp layout (128*32)
    u32 vo = (u32)u_begin * 128u;
    i32x4 ka0 = *(const i32x4*)&Kg[ko];
    i32x4 ka1 = *(const i32x4*)&Kg[ko + 8];
    i32x4 va0 = *(const i32x4*)&Vg[vo];
    i32x4 va1 = *(const i32x4*)&Vg[vo + 8];

    for (int u = u_begin; u < u_end; ++u) {
        __syncthreads();                       // prior compute done with LDS
        *(i32x4*)&Ks[krow][kcc] = ka0;
        *(i32x4*)&Ks[krow][kcc + 8] = ka1;
        *(i32x4*)&Vt[vrow][vcc] = va0;
        *(i32x4*)&Vt[vrow][vcc + 8] = va1;
        if (u + 1 < u_end) {                   // prefetch next unit (overlaps compute)
            ko += 4096u; vo += 128u;
            ka0 = *(const i32x4*)&Kg[ko];
            ka1 = *(const i32x4*)&Kg[ko + 8];
            va0 = *(const i32x4*)&Vg[vo];
            va1 = *(const i32x4*)&Vg[vo + 8];
        }
        __syncthreads();                       // LDS ready

#pragma unroll
        for (int sub = 0; sub < 2; ++sub) {
            const int kt64 = u * 2 + sub;
            if (kt64 <= qt) {
                // QK^T (swapped): S^T frag f: rows = keys f*16+g*4+i, col = q = k15
                f32x4 s[4];
#pragma unroll
                for (int f = 0; f < 4; f++) {
                    bf16x8 kf = *(const bf16x8*)&Ks[sub * 64 + f * 16 + k15][g * 8];
                    f32x4 z = {0.f, 0.f, 0.f, 0.f};
                    s[f] = __builtin_amdgcn_mfma_f32_16x16x32_bf16(kf, qf, z, 0, 0, 0);
                }
                if (kt64 == qt) { // diagonal: mask key_local > w*16 + q_local
#pragma unroll
                    for (int f = 0; f < 4; f++)
#pragma unroll
                        for (int i = 0; i < 4; i++)
                            if (f * 16 + g * 4 + i > qloc) s[f][i] = -16384.f;
                }
                // P = exp2(S) raw, pack bf16, write P^T
#pragma unroll
                for (int f = 0; f < 4; f++) {
                    u32 lo = cvt_pk_bf16(exp2_raw(s[f][0]), exp2_raw(s[f][1]));
                    u32 hi = cvt_pk_bf16(exp2_raw(s[f][2]), exp2_raw(s[f][3]));
                    uint2 pk; pk.x = lo; pk.y = hi;
                    *(uint2*)&Pt[w][k15][f * 16 + g * 4] = pk;
                }
                asm volatile("" ::: "memory");
                // PV: A[m=q][k=key] from Pt, B[n=d][k=key] from Vt
#pragma unroll
                for (int kh = 0; kh < 2; kh++) {
                    bf16x8 pa = *(const bf16x8*)&Pt[w][k15][kh * 32 + g * 8];
                    bf16x8 v0 = *(const bf16x8*)&Vt[k15][sub * 64 + kh * 32 + g * 8];
                    bf16x8 v1 = *(const bf16x8*)&Vt[16 + k15][sub * 64 + kh * 32 + g * 8];
                    y0 = __builtin_amdgcn_mfma_f32_16x16x32_bf16(pa, v0, y0, 0, 0, 0);
                    y1 = __builtin_amdgcn_mfma_f32_16x16x32_bf16(pa, v1, y1, 0, 0, 0);
                }
                asm volatile("" ::: "memory");
            }
        }
    }

    if (nc == 1) { // single chunk: normalize by l (= y1 col 15 = ones-column) and write
#pragma unroll
        for (int i = 0; i < 4; i++) {
            float li = __shfl(y1[i], (lane & 48) + 15);
            float inv = 1.0f / li;
            int rowY = b * T_SEQ + q0 + w * 16 + g * 4 + i;
            u16* yr = &Ybuf[(size_t)rowY * 192 + h * 21];
            yr[k15] = f2bf(y0[i] * inv);
            if (k15 < 5) yr[16 + k15] = f2bf(y1[i] * inv);
        }
    } else { // bf16 partials (denominator at d=31)
#pragma unroll
        for (int i = 0; i < 4; i++) {
            size_t pb = (size_t)ci * PART_SLOT +
                        (((size_t)bh << 11) + q0 + w * 16 + g * 4 + i) * 32;
            Part[pb + k15] = f2bf(y0[i]);
            Part[pb + 16 + k15] = f2bf(y1[i]);
        }
    }
}

// combine nc partial slots for rows t >= 512, normalize, write Ybuf
__global__ __launch_bounds__(256) void attn_reduce(const u16* __restrict__ Part, u16* __restrict__ Ybuf) {
    int gid = blockIdx.x * 256 + threadIdx.x; // 36 * 1536 * 32
    int d = gid & 31;
    int rest = gid >> 5;
    int t = 512 + (rest % 1536);
    int bh = rest / 1536;
    int b = bh / N_HEADS, h = bh - b * N_HEADS;
    int qt = t >> 6;
    int nc = (qt >> 3) + 1;
    size_t base = (((size_t)bh << 11) + t) * 32;
    float l = 0.f, v = 0.f;
    for (int ci = 0; ci < nc; ci++) {
        l += bf2f(Part[(size_t)ci * PART_SLOT + base + 31]);
        if (d < 21) v += bf2f(Part[(size_t)ci * PART_SLOT + base + d]);
    }
    if (d < 21) Ybuf[(size_t)(b * T_SEQ + t) * 192 + h * 21 + d] = f2bf(v / l);
}

// ---------------- launch ----------------

extern "C" void kernel_launch(void* const* d_in, const int* in_sizes, int n_in,
                              void* d_out, int out_size, void* d_ws, size_t ws_size,
                              hipStream_t stream) {
    const float* x  = (const float*)d_in[0];
    const float* Wq = (const float*)d_in[1];
    const float* Wk = (const float*)d_in[2];
    const float* Wv = (const float*)d_in[3];
    const float* Wo = (const float*)d_in[4];
    float* out = (float*)d_out;

    char* p = (char*)d_ws;
    auto alloc = [&](size_t bytes) { char* r = p; p += (bytes + 255) & ~(size_t)255; return r; };
    u16*   QpKp   = (u16*)alloc((size_t)ROWS * CDIM * 2);   // Qp | Kp
    u16*   qkv    = (u16*)alloc((size_t)ROWS * CDIM * 2);
    u16*   WcT    = (u16*)alloc((size_t)576 * 576 * 2);
    u16*   WoSubT = (u16*)alloc((size_t)576 * 192 * 2);
    float* cosT   = (float*)alloc((size_t)T_SEQ * 21 * 4);
    float* sinT   = (float*)alloc((size_t)T_SEQ * 21 * 4);
    u16*   Vp     = (u16*)alloc((size_t)NBH * 32 * T_SEQ * 2);
    u16*   Ybuf   = (u16*)alloc((size_t)ROWS * 192 * 2);
    u16*   Part   = (u16*)alloc((size_t)4 * PART_SLOT * 2);

    u16* Qp = QpKp;
    u16* Kp = QpKp + (size_t)NBH * T_SEQ * 32;

    prep_wt<<<dim3((576 * 576 + 255) / 256), dim3(256), 0, stream>>>(Wq, Wk, Wv, Wo, WcT, WoSubT, cosT, sinT);

    // QKV projection: [8192,576(f32)] x [576,567(->576)] — XCD-aligned 1-D grid (64 m x 9 n)
    gemm_mfma<1, 0><<<dim3(64 * 9), dim3(256), 0, stream>>>((const void*)x, WcT, (void*)qkv, 576, 576, 576, 576);

    // merged rope + repack (Q/K roped rows, V d-major transpose)
    repack_qkv<<<dim3(T_SEQ / 64, NBH), dim3(256), 0, stream>>>(qkv, cosT, sinT, Qp, Kp, Vp);

    // balanced split-K MFMA flash attention + combine
    attn_mfma<<<dim3(80, NBH), dim3(256), 0, stream>>>(Qp, Kp, Vp, Ybuf, Part);
    attn_reduce<<<dim3(NBH * 1536 * 32 / 256), dim3(256), 0, stream>>>(Part, Ybuf);

    // output GEMM: [8192,192] x [192,576] — XCD-aligned 1-D grid (64 m x 9 n; N=576!)
    gemm_mfma<0, 1><<<dim3(64 * 9), dim3(256), 0, stream>>>((const void*)Ybuf, WoSubT, (void*)out, 192, 192, 192, 576);
}

// Round 11
// 79.827 us; speedup vs baseline: 1.3802x; 1.1575x over previous
//
#include <hip/hip_runtime.h>
#include <hip/hip_bf16.h>

typedef unsigned short u16;
typedef unsigned int u32;
typedef __attribute__((ext_vector_type(8))) short bf16x8;
typedef __attribute__((ext_vector_type(4))) float f32x4;
typedef __attribute__((ext_vector_type(4))) int i32x4;

#define N_HEADS 9
#define T_SEQ 2048
#define BATCH 4
#define CDIM 576
#define ROWS (BATCH * T_SEQ) /* 8192 */
#define NBH (BATCH * N_HEADS) /* 36 */
#define PART_SLOT ((size_t)NBH * T_SEQ * 32) /* u16 elements per partial slot */

__device__ __forceinline__ u16 f2bf(float f) {
    u32 u = __float_as_uint(f);
    u32 r = u + 0x7FFFu + ((u >> 16) & 1u);
    return (u16)(r >> 16);
}
__device__ __forceinline__ float bf2f(u16 u) { return __uint_as_float(((u32)u) << 16); }
__device__ __forceinline__ u32 cvt_pk_bf16(float lo, float hi) {
    u32 r;
    asm("v_cvt_pk_bf16_f32 %0, %1, %2" : "=v"(r) : "v"(lo), "v"(hi));
    return r;
}
__device__ __forceinline__ float exp2_raw(float x) {
    float r;
    asm("v_exp_f32 %0, %1" : "=v"(r) : "v"(x));
    return r;
}

// ---------------- merged prep: weights + trig tables ----------------
__global__ __launch_bounds__(256) void prep_wt(const float* __restrict__ Wq, const float* __restrict__ Wk,
                                               const float* __restrict__ Wv, const float* __restrict__ Wo,
                                               u16* __restrict__ WcT, u16* __restrict__ WoSubT,
                                               float* __restrict__ cosT, float* __restrict__ sinT) {
    int idx = blockIdx.x * 256 + threadIdx.x;
    if (idx < 576 * 576) {
        int n = idx / 576, k = idx - n * 576;
        float v;
        if (n < 189)      v = Wq[(size_t)k * 576 + (n / 21) * 64 + (n % 21)];
        else if (n < 378) v = Wk[(size_t)k * 189 + (n - 189)];
        else if (n < 567) v = Wv[(size_t)k * 189 + (n - 378)];
        else              v = 0.f;
        WcT[(size_t)n * 576 + k] = f2bf(v);
    }
    if (idx < 576 * 192) {
        int n = idx / 192, k = idx - n * 192;
        float v = 0.f;
        if (k < 189) v = Wo[(size_t)((k / 21) * 64 + (k % 21)) * 576 + n];
        WoSubT[(size_t)n * 192 + k] = f2bf(v);
    }
    if (idx < T_SEQ * 21) {
        int t = idx / 21, d = idx - t * 21;
        int i = (d < 11) ? d : d - 11;
        float e = (2.0f * (float)i) / 21.0f;
        float invf = exp2f(-e * 13.287712379549449f); // 10000^-e
        float ang = (float)t * invf;
        cosT[idx] = cosf(ang);
        sinT[idx] = sinf(ang);
    }
}

// ---------------- bf16 MFMA GEMM: C[M,N] = A[M,K] * BT[N,K]^T ----------------
// 128x64 tile, 4 waves. 1-D grid, m = bx&63, n = bx>>6: blocks sharing an A panel (same m,
// different n) are 64 apart in dispatch index ≡ same (mod 8) -> same XCD L2 -> A fetched once.

template <int AF32, int OUTF32>
__global__ __launch_bounds__(256) void gemm_mfma(const void* __restrict__ Av, const u16* __restrict__ BT,
                                                 void* __restrict__ Cout, int K, int lda, int ldbt, int ldc) {
    __shared__ u16 As[128][32];
    __shared__ u16 Bs[64][32];
    const int tid = threadIdx.x;
    const int lane = tid & 63, w = tid >> 6;
    const int m0 = (blockIdx.x & 63) * 128, n0 = (blockIdx.x >> 6) * 64;
    const int k15 = lane & 15, g = lane >> 4;

    const int arow = tid >> 1;          // 0..127
    const int ac0 = (tid & 1) * 2;      // chunks ac0, ac0+1
    const int brow = tid >> 2, bc = tid & 3;

    f32x4 zero = {0.f, 0.f, 0.f, 0.f};
    f32x4 acc[2][4];
#pragma unroll
    for (int hf = 0; hf < 2; hf++)
#pragma unroll
        for (int n = 0; n < 4; n++) acc[hf][n] = zero;

    const float* Af = (const float*)Av;
    const u16*   Ab = (const u16*)Av;

    float4 af0, af1, af2, af3;
    i32x4 av0, av1;
    if (AF32) {
        const float* ap = &Af[(size_t)(m0 + arow) * lda + ac0 * 8];
        af0 = *(const float4*)&ap[0];
        af1 = *(const float4*)&ap[4];
        af2 = *(const float4*)&ap[8];
        af3 = *(const float4*)&ap[12];
    } else {
        av0 = *(const i32x4*)&Ab[(size_t)(m0 + arow) * lda + ac0 * 8];
        av1 = *(const i32x4*)&Ab[(size_t)(m0 + arow) * lda + (ac0 + 1) * 8];
    }
    i32x4 bv = *(const i32x4*)&BT[(size_t)(n0 + brow) * ldbt + bc * 8];

    for (int k0 = 0; k0 < K; k0 += 32) {
        __syncthreads();
        if (AF32) {
            i32x4 w0, w1;
            w0[0] = (int)cvt_pk_bf16(af0.x, af0.y); w0[1] = (int)cvt_pk_bf16(af0.z, af0.w);
            w0[2] = (int)cvt_pk_bf16(af1.x, af1.y); w0[3] = (int)cvt_pk_bf16(af1.z, af1.w);
            w1[0] = (int)cvt_pk_bf16(af2.x, af2.y); w1[1] = (int)cvt_pk_bf16(af2.z, af2.w);
            w1[2] = (int)cvt_pk_bf16(af3.x, af3.y); w1[3] = (int)cvt_pk_bf16(af3.z, af3.w);
            *(i32x4*)&As[arow][(ac0 ^ (arow & 3)) * 8] = w0;
            *(i32x4*)&As[arow][((ac0 + 1) ^ (arow & 3)) * 8] = w1;
        } else {
            *(i32x4*)&As[arow][(ac0 ^ (arow & 3)) * 8] = av0;
            *(i32x4*)&As[arow][((ac0 + 1) ^ (arow & 3)) * 8] = av1;
        }
        *(i32x4*)&Bs[brow][(bc ^ (brow & 3)) * 8] = bv;
        __syncthreads();
        int k1 = k0 + 32;
        if (k1 < K) {
            if (AF32) {
                const float* ap = &Af[(size_t)(m0 + arow) * lda + k1 + ac0 * 8];
                af0 = *(const float4*)&ap[0];
                af1 = *(const float4*)&ap[4];
                af2 = *(const float4*)&ap[8];
                af3 = *(const float4*)&ap[12];
            } else {
                av0 = *(const i32x4*)&Ab[(size_t)(m0 + arow) * lda + k1 + ac0 * 8];
                av1 = *(const i32x4*)&Ab[(size_t)(m0 + arow) * lda + k1 + (ac0 + 1) * 8];
            }
            bv = *(const i32x4*)&BT[(size_t)(n0 + brow) * ldbt + k1 + bc * 8];
        }
        const int ar0 = w * 32 + k15;
        bf16x8 a0 = *(const bf16x8*)&As[ar0][(g ^ (ar0 & 3)) * 8];
        bf16x8 a1 = *(const bf16x8*)&As[ar0 + 16][(g ^ (ar0 & 3)) * 8];
#pragma unroll
        for (int n = 0; n < 4; n++) {
            int br = n * 16 + k15;
            bf16x8 b = *(const bf16x8*)&Bs[br][(g ^ (br & 3)) * 8];
            acc[0][n] = __builtin_amdgcn_mfma_f32_16x16x32_bf16(a0, b, acc[0][n], 0, 0, 0);
            acc[1][n] = __builtin_amdgcn_mfma_f32_16x16x32_bf16(a1, b, acc[1][n], 0, 0, 0);
        }
    }
#pragma unroll
    for (int hf = 0; hf < 2; hf++)
#pragma unroll
        for (int n = 0; n < 4; n++)
#pragma unroll
            for (int i = 0; i < 4; i++) {
                int row = m0 + w * 32 + hf * 16 + g * 4 + i;
                int col = n0 + n * 16 + k15;
                float v = acc[hf][n][i];
                if (OUTF32) ((float*)Cout)[(size_t)row * ldc + col] = v;
                else        ((u16*)Cout)[(size_t)row * ldc + col] = f2bf(v);
            }
}

// ---------------- merged repack: rope Q/K + V transpose, vectorized loads ----------------
// Qp[bh][t][32] (roped, scaled by 0.125*log2e), Kp[bh][t][32] (roped),
// Vp[bh][32][2048] d-major (rows 21..30 zero, row 31 = 1.0 ones/denominator column).
// Phase 0: cooperative 16B vector loads of q/k/v row segments (16B-aligned windows) into LDS.
// Phase 1: rope from LDS. Phase 2: V d-major transpose from LDS.

__global__ __launch_bounds__(256) void repack_qkv(const u16* __restrict__ qkv,
                                                  const float* __restrict__ cosT,
                                                  const float* __restrict__ sinT,
                                                  u16* __restrict__ Qp, u16* __restrict__ Kp,
                                                  u16* __restrict__ Vp) {
    __shared__ u16 Qs[64][40];
    __shared__ u16 Ksh[64][40];
    __shared__ u16 Vsh[64][40];
    const int tid = threadIdx.x;
    const int bh = blockIdx.y;
    const int b = bh / N_HEADS, h = bh - b * N_HEADS;
    const int t0 = blockIdx.x * 64;

    const int qa = (h * 21) & ~7,        qoff = h * 21 - qa;
    const int ka = (189 + h * 21) & ~7,  koff = 189 + h * 21 - ka;
    const int va = (378 + h * 21) & ~7,  voff = 378 + h * 21 - va;

    // phase 0: 3 streams x 64 rows x 4 chunks (16B each), aligned windows
#pragma unroll
    for (int it = 0; it < 3; ++it) {
        int idx = tid + it * 256;  // 0..767
        int row = idx / 12;
        int r12 = idx - row * 12;
        int stream = r12 >> 2, chunk = r12 & 3;
        int off = (stream == 0) ? qa : (stream == 1) ? ka : va;
        const u16* src = qkv + (size_t)(b * T_SEQ + t0 + row) * CDIM + off + chunk * 8;
        i32x4 v = *(const i32x4*)src;
        u16* dst = (stream == 0) ? &Qs[row][0] : (stream == 1) ? &Ksh[row][0] : &Vsh[row][0];
        *(i32x4*)&dst[chunk * 8] = v;
    }
    __syncthreads();

    // phase 1: rope Q/K for d = c*8 .. c*8+7 (read from LDS)
    const int r = tid >> 2, c = tid & 3;
    const int t = t0 + r;
    const float* cr = cosT + t * 21;
    const float* sr = sinT + t * 21;
    u32 wq[4] = {0, 0, 0, 0}, wk[4] = {0, 0, 0, 0};
    const float sc = 0.18033688011112042f; // 0.125 * log2(e)
#pragma unroll
    for (int j = 0; j < 8; j++) {
        int d = c * 8 + j;
        float vq = 0.f, vk = 0.f;
        if (d < 21) {
            int pd = (d < 11) ? d + 10 : d - 11;
            float cc = cr[d], ss = sr[d];
            float qv = bf2f(Qs[r][qoff + d]),  qp = bf2f(Qs[r][qoff + pd]);
            float kv = bf2f(Ksh[r][koff + d]), kp = bf2f(Ksh[r][koff + pd]);
            float rq = (d < 11) ? -qp : qp;
            float rk = (d < 11) ? -kp : kp;
            vq = (qv * cc + rq * ss) * sc;
            vk = kv * cc + rk * ss;
        }
        wq[j >> 1] |= (u32)f2bf(vq) << ((j & 1) * 16);
        wk[j >> 1] |= (u32)f2bf(vk) << ((j & 1) * 16);
    }
    size_t obase = ((size_t)bh * T_SEQ + t) * 32 + c * 8;
    i32x4 q4; q4[0] = (int)wq[0]; q4[1] = (int)wq[1]; q4[2] = (int)wq[2]; q4[3] = (int)wq[3];
    i32x4 k4; k4[0] = (int)wk[0]; k4[1] = (int)wk[1]; k4[2] = (int)wk[2]; k4[3] = (int)wk[3];
    *(i32x4*)&Qp[obase] = q4;
    *(i32x4*)&Kp[obase] = k4;

    // phase 2: V d-major transpose, 8 keys (16B) per thread (LDS read-only, no extra barrier)
    const int dv = tid >> 3, tc = tid & 7;
    u32 wv[4];
#pragma unroll
    for (int j = 0; j < 4; j++) {
        u16 lo, hi;
        if (dv < 21)      { lo = Vsh[tc * 8 + j * 2][voff + dv]; hi = Vsh[tc * 8 + j * 2 + 1][voff + dv]; }
        else if (dv == 31){ lo = 0x3F80; hi = 0x3F80; }
        else              { lo = 0; hi = 0; }
        wv[j] = (u32)lo | ((u32)hi << 16);
    }
    i32x4 v4; v4[0] = (int)wv[0]; v4[1] = (int)wv[1]; v4[2] = (int)wv[2]; v4[3] = (int)wv[3];
    *(i32x4*)&Vp[((size_t)bh * 32 + dv) * T_SEQ + t0 + tc * 8] = v4;
}

// ---------------- split-K MFMA flash attention (double-Pt sub-pipelined) ----------------
// Fixed-base softmax (bounded scores) => linear in keys => split-K partials.
// nc(qt) = qt/8+1 chunks of <=4 units (128 keys each); 80 chunks/bh, heavy-first.
// Per 128-key unit the two 64-key sub-tiles use INDEPENDENT Pt buffers so QK/softmax/PV of
// sub0 and sub1 form two independent streams the scheduler can interleave (ILP doubling).

__global__ __launch_bounds__(256) void attn_mfma(const u16* __restrict__ Qp,
                                                 const u16* __restrict__ Kp,
                                                 const u16* __restrict__ Vp,
                                                 u16* __restrict__ Ybuf,
                                                 u16* __restrict__ Part) {
    __shared__ u16 Ks[128][40];       // 80B rows (5 quads)
    __shared__ u16 Vt[32][136];       // 272B rows (17 quads)
    __shared__ u16 Pt[2][4][16][72];  // [sub][wave][q][key] — double-buffered by sub
    const int tid = threadIdx.x;
    const int lane = tid & 63, w = tid >> 6;
    const int bh = blockIdx.y;
    const int b = bh / N_HEADS, h = bh - b * N_HEADS;
    const int k15 = lane & 15, g = lane >> 4;

    int bx = blockIdx.x, qt, ci;
    if (bx < 32)      { qt = 31 - (bx >> 2); ci = bx & 3; }                    // nc=4
    else if (bx < 56) { int r = bx - 32; int q3 = r / 3; qt = 23 - q3; ci = r - q3 * 3; } // nc=3
    else if (bx < 72) { int r = bx - 56; qt = 15 - (r >> 1); ci = r & 1; }     // nc=2
    else              { qt = 79 - bx; ci = 0; }                                 // nc=1
    const int q0 = qt * 64;
    const int n128 = (qt + 2) >> 1;       // 128-key units covering keys 0..q0+63
    const int nc = (qt >> 3) + 1;
    const int u_begin = (ci * n128) / nc;
    const int u_end = ((ci + 1) * n128) / nc;

    // per-thread staging source pointers
    const u16* Kg = Kp + (((size_t)bh << 11) * 32) + (tid >> 1) * 32 + (tid & 1) * 16;
    const u16* Vg = Vp + (size_t)bh * 32 * T_SEQ + (size_t)(tid >> 3) * T_SEQ + (tid & 7) * 16;
    const int krow = tid >> 1, kcc = (tid & 1) * 16;
    const int vrow = tid >> 3, vcc = (tid & 7) * 16;

    // Q B-fragment held in regs: B[n=q][k=d]
    bf16x8 qf = *(const bf16x8*)&Qp[(((size_t)bh << 11) + q0 + w * 16 + k15) * 32 + g * 8];

    f32x4 y0 = {0.f, 0.f, 0.f, 0.f}, y1 = {0.f, 0.f, 0.f, 0.f};
    const int qloc = w * 16 + k15;

    // prologue loads (unit u_begin)
    u32 ko = (u32)u_begin * 4096u;  // u16 elems per unit in Kp layout (128*32)
    u32 vo = (u32)u_begin * 128u;
    i32x4 ka0 = *(const i32x4*)&Kg[ko];
    i32x4 ka1 = *(const i32x4*)&Kg[ko + 8];
    i32x4 va0 = *(const i32x4*)&Vg[vo];
    i32x4 va1 = *(const i32x4*)&Vg[vo + 8];

    for (int u = u_begin; u < u_end; ++u) {
        __syncthreads();                       // prior compute done with LDS
        *(i32x4*)&Ks[krow][kcc] = ka0;
        *(i32x4*)&Ks[krow][kcc + 8] = ka1;
        *(i32x4*)&Vt[vrow][vcc] = va0;
        *(i32x4*)&Vt[vrow][vcc + 8] = va1;
        if (u + 1 < u_end) {                   // prefetch next unit (overlaps compute)
            ko += 4096u; vo += 128u;
            ka0 = *(const i32x4*)&Kg[ko];
            ka1 = *(const i32x4*)&Kg[ko + 8];
            va0 = *(const i32x4*)&Vg[vo];
            va1 = *(const i32x4*)&Vg[vo + 8];
        }
        __syncthreads();                       // LDS ready

        const int kt0 = u * 2;
        const bool has1 = (kt0 + 1 <= qt);

        // QK^T both subs (independent MFMA streams)
        f32x4 s0[4], s1[4];
#pragma unroll
        for (int f = 0; f < 4; f++) {
            bf16x8 kf = *(const bf16x8*)&Ks[f * 16 + k15][g * 8];
            f32x4 z = {0.f, 0.f, 0.f, 0.f};
            s0[f] = __builtin_amdgcn_mfma_f32_16x16x32_bf16(kf, qf, z, 0, 0, 0);
        }
        if (has1) {
#pragma unroll
            for (int f = 0; f < 4; f++) {
                bf16x8 kf = *(const bf16x8*)&Ks[64 + f * 16 + k15][g * 8];
                f32x4 z = {0.f, 0.f, 0.f, 0.f};
                s1[f] = __builtin_amdgcn_mfma_f32_16x16x32_bf16(kf, qf, z, 0, 0, 0);
            }
        }
        if (kt0 == qt) { // diagonal in sub0 (qt even)
#pragma unroll
            for (int f = 0; f < 4; f++)
#pragma unroll
                for (int i = 0; i < 4; i++)
                    if (f * 16 + g * 4 + i > qloc) s0[f][i] = -16384.f;
        }
        if (has1 && kt0 + 1 == qt) { // diagonal in sub1 (qt odd)
#pragma unroll
            for (int f = 0; f < 4; f++)
#pragma unroll
                for (int i = 0; i < 4; i++)
                    if (f * 16 + g * 4 + i > qloc) s1[f][i] = -16384.f;
        }

        // P = exp2(S), pack bf16, write each sub's own Pt buffer
#pragma unroll
        for (int f = 0; f < 4; f++) {
            u32 lo = cvt_pk_bf16(exp2_raw(s0[f][0]), exp2_raw(s0[f][1]));
            u32 hi = cvt_pk_bf16(exp2_raw(s0[f][2]), exp2_raw(s0[f][3]));
            uint2 pk; pk.x = lo; pk.y = hi;
            *(uint2*)&Pt[0][w][k15][f * 16 + g * 4] = pk;
        }
        if (has1) {
#pragma unroll
            for (int f = 0; f < 4; f++) {
                u32 lo = cvt_pk_bf16(exp2_raw(s1[f][0]), exp2_raw(s1[f][1]));
                u32 hi = cvt_pk_bf16(exp2_raw(s1[f][2]), exp2_raw(s1[f][3]));
                uint2 pk; pk.x = lo; pk.y = hi;
                *(uint2*)&Pt[1][w][k15][f * 16 + g * 4] = pk;
            }
        }
        asm volatile("" ::: "memory"); // Pt writes ordered before reads (wave-local)

        // PV both subs: A[m=q][k=key] from Pt[sub], B[n=d][k=key] from Vt
#pragma unroll
        for (int kh = 0; kh < 2; kh++) {
            bf16x8 pa = *(const bf16x8*)&Pt[0][w][k15][kh * 32 + g * 8];
            bf16x8 v0 = *(const bf16x8*)&Vt[k15][kh * 32 + g * 8];
            bf16x8 v1 = *(const bf16x8*)&Vt[16 + k15][kh * 32 + g * 8];
            y0 = __builtin_amdgcn_mfma_f32_16x16x32_bf16(pa, v0, y0, 0, 0, 0);
            y1 = __builtin_amdgcn_mfma_f32_16x16x32_bf16(pa, v1, y1, 0, 0, 0);
        }
        if (has1) {
#pragma unroll
            for (int kh = 0; kh < 2; kh++) {
                bf16x8 pa = *(const bf16x8*)&Pt[1][w][k15][kh * 32 + g * 8];
                bf16x8 v0 = *(const bf16x8*)&Vt[k15][64 + kh * 32 + g * 8];
                bf16x8 v1 = *(const bf16x8*)&Vt[16 + k15][64 + kh * 32 + g * 8];
                y0 = __builtin_amdgcn_mfma_f32_16x16x32_bf16(pa, v0, y0, 0, 0, 0);
                y1 = __builtin_amdgcn_mfma_f32_16x16x32_bf16(pa, v1, y1, 0, 0, 0);
            }
        }
        asm volatile("" ::: "memory"); // Pt reads done before next unit's writes
    }

    if (nc == 1) { // single chunk: normalize by l (= y1 col 15 = ones-column) and write
#pragma unroll
        for (int i = 0; i < 4; i++) {
            float li = __shfl(y1[i], (lane & 48) + 15);
            float inv = 1.0f / li;
            int rowY = b * T_SEQ + q0 + w * 16 + g * 4 + i;
            u16* yr = &Ybuf[(size_t)rowY * 192 + h * 21];
            yr[k15] = f2bf(y0[i] * inv);
            if (k15 < 5) yr[16 + k15] = f2bf(y1[i] * inv);
        }
    } else { // bf16 partials (denominator at d=31)
#pragma unroll
        for (int i = 0; i < 4; i++) {
            size_t pb = (size_t)ci * PART_SLOT +
                        (((size_t)bh << 11) + q0 + w * 16 + g * 4 + i) * 32;
            Part[pb + k15] = f2bf(y0[i]);
            Part[pb + 16 + k15] = f2bf(y1[i]);
        }
    }
}

// combine nc partial slots for rows t >= 512, normalize, write Ybuf
__global__ __launch_bounds__(256) void attn_reduce(const u16* __restrict__ Part, u16* __restrict__ Ybuf) {
    int gid = blockIdx.x * 256 + threadIdx.x; // 36 * 1536 * 32
    int d = gid & 31;
    int rest = gid >> 5;
    int t = 512 + (rest % 1536);
    int bh = rest / 1536;
    int b = bh / N_HEADS, h = bh - b * N_HEADS;
    int qt = t >> 6;
    int nc = (qt >> 3) + 1;
    size_t base = (((size_t)bh << 11) + t) * 32;
    float l = 0.f, v = 0.f;
    for (int ci = 0; ci < nc; ci++) {
        l += bf2f(Part[(size_t)ci * PART_SLOT + base + 31]);
        if (d < 21) v += bf2f(Part[(size_t)ci * PART_SLOT + base + d]);
    }
    if (d < 21) Ybuf[(size_t)(b * T_SEQ + t) * 192 + h * 21 + d] = f2bf(v / l);
}

// ---------------- launch ----------------

extern "C" void kernel_launch(void* const* d_in, const int* in_sizes, int n_in,
                              void* d_out, int out_size, void* d_ws, size_t ws_size,
                              hipStream_t stream) {
    const float* x  = (const float*)d_in[0];
    const float* Wq = (const float*)d_in[1];
    const float* Wk = (const float*)d_in[2];
    const float* Wv = (const float*)d_in[3];
    const float* Wo = (const float*)d_in[4];
    float* out = (float*)d_out;

    char* p = (char*)d_ws;
    auto alloc = [&](size_t bytes) { char* r = p; p += (bytes + 255) & ~(size_t)255; return r; };
    u16*   QpKp   = (u16*)alloc((size_t)ROWS * CDIM * 2);   // Qp | Kp
    u16*   qkv    = (u16*)alloc((size_t)ROWS * CDIM * 2);
    u16*   WcT    = (u16*)alloc((size_t)576 * 576 * 2);
    u16*   WoSubT = (u16*)alloc((size_t)576 * 192 * 2);
    float* cosT   = (float*)alloc((size_t)T_SEQ * 21 * 4);
    float* sinT   = (float*)alloc((size_t)T_SEQ * 21 * 4);
    u16*   Vp     = (u16*)alloc((size_t)NBH * 32 * T_SEQ * 2);
    u16*   Ybuf   = (u16*)alloc((size_t)ROWS * 192 * 2);
    u16*   Part   = (u16*)alloc((size_t)4 * PART_SLOT * 2);

    u16* Qp = QpKp;
    u16* Kp = QpKp + (size_t)NBH * T_SEQ * 32;

    prep_wt<<<dim3((576 * 576 + 255) / 256), dim3(256), 0, stream>>>(Wq, Wk, Wv, Wo, WcT, WoSubT, cosT, sinT);

    // QKV projection: [8192,576(f32)] x [576,567(->576)] — XCD-aligned 1-D grid (64 m x 9 n)
    gemm_mfma<1, 0><<<dim3(64 * 9), dim3(256), 0, stream>>>((const void*)x, WcT, (void*)qkv, 576, 576, 576, 576);

    // merged rope + repack (vectorized loads; Q/K roped rows, V d-major transpose)
    repack_qkv<<<dim3(T_SEQ / 64, NBH), dim3(256), 0, stream>>>(qkv, cosT, sinT, Qp, Kp, Vp);

    // balanced split-K MFMA flash attention + combine
    attn_mfma<<<dim3(80, NBH), dim3(256), 0, stream>>>(Qp, Kp, Vp, Ybuf, Part);
    attn_reduce<<<dim3(NBH * 1536 * 32 / 256), dim3(256), 0, stream>>>(Part, Ybuf);

    // output GEMM: [8192,192] x [192,576] — XCD-aligned 1-D grid (64 m x 9 n)
    gemm_mfma<0, 1><<<dim3(64 * 9), dim3(256), 0, stream>>>((const void*)Ybuf, WoSubT, (void*)out, 192, 192, 192, 576);
}

// Round 12
// 77.740 us; speedup vs baseline: 1.4172x; 1.0268x over previous
//
#include <hip/hip_runtime.h>
#include <hip/hip_bf16.h>

typedef unsigned short u16;
typedef unsigned int u32;
typedef __attribute__((ext_vector_type(8))) short bf16x8;
typedef __attribute__((ext_vector_type(4))) float f32x4;
typedef __attribute__((ext_vector_type(4))) int i32x4;

#define N_HEADS 9
#define T_SEQ 2048
#define BATCH 4
#define CDIM 576
#define ROWS (BATCH * T_SEQ) /* 8192 */
#define NBH (BATCH * N_HEADS) /* 36 */
#define PART_SLOT ((size_t)NBH * T_SEQ * 32) /* u16 elements per partial slot */

__device__ __forceinline__ u16 f2bf(float f) {
    u32 u = __float_as_uint(f);
    u32 r = u + 0x7FFFu + ((u >> 16) & 1u);
    return (u16)(r >> 16);
}
__device__ __forceinline__ float bf2f(u16 u) { return __uint_as_float(((u32)u) << 16); }
__device__ __forceinline__ u32 cvt_pk_bf16(float lo, float hi) {
    u32 r;
    asm("v_cvt_pk_bf16_f32 %0, %1, %2" : "=v"(r) : "v"(lo), "v"(hi));
    return r;
}
__device__ __forceinline__ float exp2_raw(float x) {
    float r;
    asm("v_exp_f32 %0, %1" : "=v"(r) : "v"(x));
    return r;
}

// ---------------- merged prep: weights + trig tables ----------------
__global__ __launch_bounds__(256) void prep_wt(const float* __restrict__ Wq, const float* __restrict__ Wk,
                                               const float* __restrict__ Wv, const float* __restrict__ Wo,
                                               u16* __restrict__ WcT, u16* __restrict__ WoSubT,
                                               float* __restrict__ cosT, float* __restrict__ sinT) {
    int idx = blockIdx.x * 256 + threadIdx.x;
    if (idx < 576 * 576) {
        int n = idx / 576, k = idx - n * 576;
        float v;
        if (n < 189)      v = Wq[(size_t)k * 576 + (n / 21) * 64 + (n % 21)];
        else if (n < 378) v = Wk[(size_t)k * 189 + (n - 189)];
        else if (n < 567) v = Wv[(size_t)k * 189 + (n - 378)];
        else              v = 0.f;
        WcT[(size_t)n * 576 + k] = f2bf(v);
    }
    if (idx < 576 * 192) {
        int n = idx / 192, k = idx - n * 192;
        float v = 0.f;
        if (k < 189) v = Wo[(size_t)((k / 21) * 64 + (k % 21)) * 576 + n];
        WoSubT[(size_t)n * 192 + k] = f2bf(v);
    }
    if (idx < T_SEQ * 21) {
        int t = idx / 21, d = idx - t * 21;
        int i = (d < 11) ? d : d - 11;
        float e = (2.0f * (float)i) / 21.0f;
        float invf = exp2f(-e * 13.287712379549449f); // 10000^-e
        float ang = (float)t * invf;
        cosT[idx] = cosf(ang);
        sinT[idx] = sinf(ang);
    }
}

// ---------------- bf16 MFMA GEMM: C[M,N] = A[M,K] * BT[N,K]^T ----------------
// 128x64 tile, 4 waves. 1-D grid, m = bx&63, n = bx>>6: blocks sharing an A panel land on
// the same XCD L2 -> A fetched from HBM once. AF32: A f32, converted in staging.

template <int AF32, int OUTF32>
__global__ __launch_bounds__(256) void gemm_mfma(const void* __restrict__ Av, const u16* __restrict__ BT,
                                                 void* __restrict__ Cout, int K, int lda, int ldbt, int ldc) {
    __shared__ u16 As[128][32];
    __shared__ u16 Bs[64][32];
    const int tid = threadIdx.x;
    const int lane = tid & 63, w = tid >> 6;
    const int m0 = (blockIdx.x & 63) * 128, n0 = (blockIdx.x >> 6) * 64;
    const int k15 = lane & 15, g = lane >> 4;

    const int arow = tid >> 1;          // 0..127
    const int ac0 = (tid & 1) * 2;      // chunks ac0, ac0+1
    const int brow = tid >> 2, bc = tid & 3;

    f32x4 zero = {0.f, 0.f, 0.f, 0.f};
    f32x4 acc[2][4];
#pragma unroll
    for (int hf = 0; hf < 2; hf++)
#pragma unroll
        for (int n = 0; n < 4; n++) acc[hf][n] = zero;

    const float* Af = (const float*)Av;
    const u16*   Ab = (const u16*)Av;

    float4 af0, af1, af2, af3;
    i32x4 av0, av1;
    if (AF32) {
        const float* ap = &Af[(size_t)(m0 + arow) * lda + ac0 * 8];
        af0 = *(const float4*)&ap[0];
        af1 = *(const float4*)&ap[4];
        af2 = *(const float4*)&ap[8];
        af3 = *(const float4*)&ap[12];
    } else {
        av0 = *(const i32x4*)&Ab[(size_t)(m0 + arow) * lda + ac0 * 8];
        av1 = *(const i32x4*)&Ab[(size_t)(m0 + arow) * lda + (ac0 + 1) * 8];
    }
    i32x4 bv = *(const i32x4*)&BT[(size_t)(n0 + brow) * ldbt + bc * 8];

    for (int k0 = 0; k0 < K; k0 += 32) {
        __syncthreads();
        if (AF32) {
            i32x4 w0, w1;
            w0[0] = (int)cvt_pk_bf16(af0.x, af0.y); w0[1] = (int)cvt_pk_bf16(af0.z, af0.w);
            w0[2] = (int)cvt_pk_bf16(af1.x, af1.y); w0[3] = (int)cvt_pk_bf16(af1.z, af1.w);
            w1[0] = (int)cvt_pk_bf16(af2.x, af2.y); w1[1] = (int)cvt_pk_bf16(af2.z, af2.w);
            w1[2] = (int)cvt_pk_bf16(af3.x, af3.y); w1[3] = (int)cvt_pk_bf16(af3.z, af3.w);
            *(i32x4*)&As[arow][(ac0 ^ (arow & 3)) * 8] = w0;
            *(i32x4*)&As[arow][((ac0 + 1) ^ (arow & 3)) * 8] = w1;
        } else {
            *(i32x4*)&As[arow][(ac0 ^ (arow & 3)) * 8] = av0;
            *(i32x4*)&As[arow][((ac0 + 1) ^ (arow & 3)) * 8] = av1;
        }
        *(i32x4*)&Bs[brow][(bc ^ (brow & 3)) * 8] = bv;
        __syncthreads();
        int k1 = k0 + 32;
        if (k1 < K) {
            if (AF32) {
                const float* ap = &Af[(size_t)(m0 + arow) * lda + k1 + ac0 * 8];
                af0 = *(const float4*)&ap[0];
                af1 = *(const float4*)&ap[4];
                af2 = *(const float4*)&ap[8];
                af3 = *(const float4*)&ap[12];
            } else {
                av0 = *(const i32x4*)&Ab[(size_t)(m0 + arow) * lda + k1 + ac0 * 8];
                av1 = *(const i32x4*)&Ab[(size_t)(m0 + arow) * lda + k1 + (ac0 + 1) * 8];
            }
            bv = *(const i32x4*)&BT[(size_t)(n0 + brow) * ldbt + k1 + bc * 8];
        }
        const int ar0 = w * 32 + k15;
        bf16x8 a0 = *(const bf16x8*)&As[ar0][(g ^ (ar0 & 3)) * 8];
        bf16x8 a1 = *(const bf16x8*)&As[ar0 + 16][(g ^ (ar0 & 3)) * 8];
#pragma unroll
        for (int n = 0; n < 4; n++) {
            int br = n * 16 + k15;
            bf16x8 b = *(const bf16x8*)&Bs[br][(g ^ (br & 3)) * 8];
            acc[0][n] = __builtin_amdgcn_mfma_f32_16x16x32_bf16(a0, b, acc[0][n], 0, 0, 0);
            acc[1][n] = __builtin_amdgcn_mfma_f32_16x16x32_bf16(a1, b, acc[1][n], 0, 0, 0);
        }
    }
#pragma unroll
    for (int hf = 0; hf < 2; hf++)
#pragma unroll
        for (int n = 0; n < 4; n++)
#pragma unroll
            for (int i = 0; i < 4; i++) {
                int row = m0 + w * 32 + hf * 16 + g * 4 + i;
                int col = n0 + n * 16 + k15;
                float v = acc[hf][n][i];
                if (OUTF32) ((float*)Cout)[(size_t)row * ldc + col] = v;
                else        ((u16*)Cout)[(size_t)row * ldc + col] = f2bf(v);
            }
}

// ---------------- merged repack: rope Q/K + V transpose, vectorized loads ----------------

__global__ __launch_bounds__(256) void repack_qkv(const u16* __restrict__ qkv,
                                                  const float* __restrict__ cosT,
                                                  const float* __restrict__ sinT,
                                                  u16* __restrict__ Qp, u16* __restrict__ Kp,
                                                  u16* __restrict__ Vp) {
    __shared__ u16 Qs[64][40];
    __shared__ u16 Ksh[64][40];
    __shared__ u16 Vsh[64][40];
    const int tid = threadIdx.x;
    const int bh = blockIdx.y;
    const int b = bh / N_HEADS, h = bh - b * N_HEADS;
    const int t0 = blockIdx.x * 64;

    const int qa = (h * 21) & ~7,        qoff = h * 21 - qa;
    const int ka = (189 + h * 21) & ~7,  koff = 189 + h * 21 - ka;
    const int va = (378 + h * 21) & ~7,  voff = 378 + h * 21 - va;

#pragma unroll
    for (int it = 0; it < 3; ++it) {
        int idx = tid + it * 256;  // 0..767
        int row = idx / 12;
        int r12 = idx - row * 12;
        int stream = r12 >> 2, chunk = r12 & 3;
        int off = (stream == 0) ? qa : (stream == 1) ? ka : va;
        const u16* src = qkv + (size_t)(b * T_SEQ + t0 + row) * CDIM + off + chunk * 8;
        i32x4 v = *(const i32x4*)src;
        u16* dst = (stream == 0) ? &Qs[row][0] : (stream == 1) ? &Ksh[row][0] : &Vsh[row][0];
        *(i32x4*)&dst[chunk * 8] = v;
    }
    __syncthreads();

    const int r = tid >> 2, c = tid & 3;
    const int t = t0 + r;
    const float* cr = cosT + t * 21;
    const float* sr = sinT + t * 21;
    u32 wq[4] = {0, 0, 0, 0}, wk[4] = {0, 0, 0, 0};
    const float sc = 0.18033688011112042f; // 0.125 * log2(e)
#pragma unroll
    for (int j = 0; j < 8; j++) {
        int d = c * 8 + j;
        float vq = 0.f, vk = 0.f;
        if (d < 21) {
            int pd = (d < 11) ? d + 10 : d - 11;
            float cc = cr[d], ss = sr[d];
            float qv = bf2f(Qs[r][qoff + d]),  qp = bf2f(Qs[r][qoff + pd]);
            float kv = bf2f(Ksh[r][koff + d]), kp = bf2f(Ksh[r][koff + pd]);
            float rq = (d < 11) ? -qp : qp;
            float rk = (d < 11) ? -kp : kp;
            vq = (qv * cc + rq * ss) * sc;
            vk = kv * cc + rk * ss;
        }
        wq[j >> 1] |= (u32)f2bf(vq) << ((j & 1) * 16);
        wk[j >> 1] |= (u32)f2bf(vk) << ((j & 1) * 16);
    }
    size_t obase = ((size_t)bh * T_SEQ + t) * 32 + c * 8;
    i32x4 q4; q4[0] = (int)wq[0]; q4[1] = (int)wq[1]; q4[2] = (int)wq[2]; q4[3] = (int)wq[3];
    i32x4 k4; k4[0] = (int)wk[0]; k4[1] = (int)wk[1]; k4[2] = (int)wk[2]; k4[3] = (int)wk[3];
    *(i32x4*)&Qp[obase] = q4;
    *(i32x4*)&Kp[obase] = k4;

    const int dv = tid >> 3, tc = tid & 7;
    u32 wv[4];
#pragma unroll
    for (int j = 0; j < 4; j++) {
        u16 lo, hi;
        if (dv < 21)      { lo = Vsh[tc * 8 + j * 2][voff + dv]; hi = Vsh[tc * 8 + j * 2 + 1][voff + dv]; }
        else if (dv == 31){ lo = 0x3F80; hi = 0x3F80; }
        else              { lo = 0; hi = 0; }
        wv[j] = (u32)lo | ((u32)hi << 16);
    }
    i32x4 v4; v4[0] = (int)wv[0]; v4[1] = (int)wv[1]; v4[2] = (int)wv[2]; v4[3] = (int)wv[3];
    *(i32x4*)&Vp[((size_t)bh * 32 + dv) * T_SEQ + t0 + tc * 8] = v4;
}

// ---------------- split-K MFMA flash attention: 128 q-rows/block, 8 waves ----------------
// Fixed-base softmax (bounded scores) => linear in keys => split-K partials.
// One staged 128-key unit now feeds 8 waves (128 q) => staging bytes & barriers per score
// halved vs 64-q blocks. Wave w owns q rows q0+w*16..+15; its diagonal key-tile is
// kd = 2*qt2 + (w>>2); waves skip tiles beyond kd. nc = (qt2>>2)+1 chunks (<=4 slots).

__global__ __launch_bounds__(512) void attn_mfma(const u16* __restrict__ Qp,
                                                 const u16* __restrict__ Kp,
                                                 const u16* __restrict__ Vp,
                                                 u16* __restrict__ Ybuf,
                                                 u16* __restrict__ Part) {
    __shared__ u16 Ks[128][40];       // 80B rows
    __shared__ u16 Vt[32][136];       // 272B rows
    __shared__ u16 Pt[2][8][16][72];  // [sub][wave][q][key]
    const int tid = threadIdx.x;
    const int lane = tid & 63, w = tid >> 6;   // w 0..7
    const int bh = blockIdx.y;
    const int b = bh / N_HEADS, h = bh - b * N_HEADS;
    const int k15 = lane & 15, g = lane >> 4;

    // bx -> (qt2, ci), heavy q-tiles first. nc(qt2) = (qt2>>2)+1, sum = 40.
    int qt2 = 15, ci = blockIdx.x;
    for (int q = 15; q >= 0; --q) {
        int n = (q >> 2) + 1;
        if (ci < n) { qt2 = q; break; }
        ci -= n;
    }
    const int q0 = qt2 * 128;
    const int n128 = qt2 + 1;            // 128-key units covering keys 0..q0+127
    const int nc = (qt2 >> 2) + 1;
    const int u_begin = (ci * n128) / nc;
    const int u_end = ((ci + 1) * n128) / nc;

    // staging: threads 0..255 stage K (128x32), 256..511 stage V (32x128); 2x16B each
    const bool isK = (tid < 256);
    const int krow = (tid & 255) >> 2, kc = tid & 3;       // K: rows krow, krow+64
    const int vrow = (tid & 255) >> 3, vc = tid & 7;       // V: chunks vc, vc+8
    const u16* Kg = Kp + (size_t)bh * 65536 + krow * 32 + kc * 8;
    const u16* Vg = Vp + (size_t)bh * 65536 + vrow * 2048 + vc * 8;

    // Q B-fragment held in regs: B[n=q][k=d]
    bf16x8 qf = *(const bf16x8*)&Qp[(((size_t)bh << 11) + q0 + w * 16 + k15) * 32 + g * 8];

    f32x4 y0 = {0.f, 0.f, 0.f, 0.f}, y1 = {0.f, 0.f, 0.f, 0.f};
    const int qloc = (w & 3) * 16 + k15;       // q position within its 64-aligned block
    const int kd = 2 * qt2 + (w >> 2);         // wave's diagonal 64-key tile index

    // prologue loads (unit u_begin)
    u32 off = (u32)u_begin * 4096u;            // K: u16 elems per unit (128*32)
    u32 voffu = (u32)u_begin * 128u;           // V: u16 elems per unit per row
    i32x4 r0, r1;
    if (isK) { r0 = *(const i32x4*)&Kg[off];   r1 = *(const i32x4*)&Kg[off + 2048]; }
    else     { r0 = *(const i32x4*)&Vg[voffu]; r1 = *(const i32x4*)&Vg[voffu + 64]; }

    for (int u = u_begin; u < u_end; ++u) {
        __syncthreads();                       // prior compute done with LDS
        if (isK) {
            *(i32x4*)&Ks[krow][kc * 8] = r0;
            *(i32x4*)&Ks[krow + 64][kc * 8] = r1;
        } else {
            *(i32x4*)&Vt[vrow][vc * 8] = r0;
            *(i32x4*)&Vt[vrow][vc * 8 + 64] = r1;
        }
        if (u + 1 < u_end) {                   // prefetch next unit (overlaps compute)
            off += 4096u; voffu += 128u;
            if (isK) { r0 = *(const i32x4*)&Kg[off];   r1 = *(const i32x4*)&Kg[off + 2048]; }
            else     { r0 = *(const i32x4*)&Vg[voffu]; r1 = *(const i32x4*)&Vg[voffu + 64]; }
        }
        __syncthreads();                       // LDS ready

        const int kt0 = u * 2;
        const bool do0 = (kt0 <= kd);
        const bool do1 = (kt0 + 1 <= kd);

        f32x4 s0[4], s1[4];
        if (do0) {
#pragma unroll
            for (int f = 0; f < 4; f++) {
                bf16x8 kf = *(const bf16x8*)&Ks[f * 16 + k15][g * 8];
                f32x4 z = {0.f, 0.f, 0.f, 0.f};
                s0[f] = __builtin_amdgcn_mfma_f32_16x16x32_bf16(kf, qf, z, 0, 0, 0);
            }
        }
        if (do1) {
#pragma unroll
            for (int f = 0; f < 4; f++) {
                bf16x8 kf = *(const bf16x8*)&Ks[64 + f * 16 + k15][g * 8];
                f32x4 z = {0.f, 0.f, 0.f, 0.f};
                s1[f] = __builtin_amdgcn_mfma_f32_16x16x32_bf16(kf, qf, z, 0, 0, 0);
            }
        }
        if (do0 && kt0 == kd) {
#pragma unroll
            for (int f = 0; f < 4; f++)
#pragma unroll
                for (int i = 0; i < 4; i++)
                    if (f * 16 + g * 4 + i > qloc) s0[f][i] = -16384.f;
        }
        if (do1 && kt0 + 1 == kd) {
#pragma unroll
            for (int f = 0; f < 4; f++)
#pragma unroll
                for (int i = 0; i < 4; i++)
                    if (f * 16 + g * 4 + i > qloc) s1[f][i] = -16384.f;
        }

        if (do0) {
#pragma unroll
            for (int f = 0; f < 4; f++) {
                u32 lo = cvt_pk_bf16(exp2_raw(s0[f][0]), exp2_raw(s0[f][1]));
                u32 hi = cvt_pk_bf16(exp2_raw(s0[f][2]), exp2_raw(s0[f][3]));
                uint2 pk; pk.x = lo; pk.y = hi;
                *(uint2*)&Pt[0][w][k15][f * 16 + g * 4] = pk;
            }
        }
        if (do1) {
#pragma unroll
            for (int f = 0; f < 4; f++) {
                u32 lo = cvt_pk_bf16(exp2_raw(s1[f][0]), exp2_raw(s1[f][1]));
                u32 hi = cvt_pk_bf16(exp2_raw(s1[f][2]), exp2_raw(s1[f][3]));
                uint2 pk; pk.x = lo; pk.y = hi;
                *(uint2*)&Pt[1][w][k15][f * 16 + g * 4] = pk;
            }
        }
        asm volatile("" ::: "memory"); // Pt writes ordered before reads (wave-local)

        if (do0) {
#pragma unroll
            for (int kh = 0; kh < 2; kh++) {
                bf16x8 pa = *(const bf16x8*)&Pt[0][w][k15][kh * 32 + g * 8];
                bf16x8 v0 = *(const bf16x8*)&Vt[k15][kh * 32 + g * 8];
                bf16x8 v1 = *(const bf16x8*)&Vt[16 + k15][kh * 32 + g * 8];
                y0 = __builtin_amdgcn_mfma_f32_16x16x32_bf16(pa, v0, y0, 0, 0, 0);
                y1 = __builtin_amdgcn_mfma_f32_16x16x32_bf16(pa, v1, y1, 0, 0, 0);
            }
        }
        if (do1) {
#pragma unroll
            for (int kh = 0; kh < 2; kh++) {
                bf16x8 pa = *(const bf16x8*)&Pt[1][w][k15][kh * 32 + g * 8];
                bf16x8 v0 = *(const bf16x8*)&Vt[k15][64 + kh * 32 + g * 8];
                bf16x8 v1 = *(const bf16x8*)&Vt[16 + k15][64 + kh * 32 + g * 8];
                y0 = __builtin_amdgcn_mfma_f32_16x16x32_bf16(pa, v0, y0, 0, 0, 0);
                y1 = __builtin_amdgcn_mfma_f32_16x16x32_bf16(pa, v1, y1, 0, 0, 0);
            }
        }
        asm volatile("" ::: "memory"); // Pt reads done before next unit's writes
    }

    if (nc == 1) { // qt2 < 4: single chunk, normalize by l (= y1 col 15 ones-column), write
#pragma unroll
        for (int i = 0; i < 4; i++) {
            float li = __shfl(y1[i], (lane & 48) + 15);
            float inv = 1.0f / li;
            int rowY = b * T_SEQ + q0 + w * 16 + g * 4 + i;
            u16* yr = &Ybuf[(size_t)rowY * 192 + h * 21];
            yr[k15] = f2bf(y0[i] * inv);
            if (k15 < 5) yr[16 + k15] = f2bf(y1[i] * inv);
        }
    } else { // bf16 partials (denominator at d=31)
#pragma unroll
        for (int i = 0; i < 4; i++) {
            size_t pb = (size_t)ci * PART_SLOT +
                        (((size_t)bh << 11) + q0 + w * 16 + g * 4 + i) * 32;
            Part[pb + k15] = f2bf(y0[i]);
            Part[pb + 16 + k15] = f2bf(y1[i]);
        }
    }
}

// combine nc partial slots for rows t >= 512, normalize, write Ybuf. nc = (t>>9)+1.
__global__ __launch_bounds__(256) void attn_reduce(const u16* __restrict__ Part, u16* __restrict__ Ybuf) {
    int gid = blockIdx.x * 256 + threadIdx.x; // 36 * 1536 * 32
    int d = gid & 31;
    int rest = gid >> 5;
    int t = 512 + (rest % 1536);
    int bh = rest / 1536;
    int b = bh / N_HEADS, h = bh - b * N_HEADS;
    int nc = (t >> 9) + 1;
    size_t base = (((size_t)bh << 11) + t) * 32;
    float l = 0.f, v = 0.f;
    for (int ci = 0; ci < nc; ci++) {
        l += bf2f(Part[(size_t)ci * PART_SLOT + base + 31]);
        if (d < 21) v += bf2f(Part[(size_t)ci * PART_SLOT + base + d]);
    }
    if (d < 21) Ybuf[(size_t)(b * T_SEQ + t) * 192 + h * 21 + d] = f2bf(v / l);
}

// ---------------- launch ----------------

extern "C" void kernel_launch(void* const* d_in, const int* in_sizes, int n_in,
                              void* d_out, int out_size, void* d_ws, size_t ws_size,
                              hipStream_t stream) {
    const float* x  = (const float*)d_in[0];
    const float* Wq = (const float*)d_in[1];
    const float* Wk = (const float*)d_in[2];
    const float* Wv = (const float*)d_in[3];
    const float* Wo = (const float*)d_in[4];
    float* out = (float*)d_out;

    char* p = (char*)d_ws;
    auto alloc = [&](size_t bytes) { char* r = p; p += (bytes + 255) & ~(size_t)255; return r; };
    u16*   QpKp   = (u16*)alloc((size_t)ROWS * CDIM * 2);   // Qp | Kp
    u16*   qkv    = (u16*)alloc((size_t)ROWS * CDIM * 2);
    u16*   WcT    = (u16*)alloc((size_t)576 * 576 * 2);
    u16*   WoSubT = (u16*)alloc((size_t)576 * 192 * 2);
    float* cosT   = (float*)alloc((size_t)T_SEQ * 21 * 4);
    float* sinT   = (float*)alloc((size_t)T_SEQ * 21 * 4);
    u16*   Vp     = (u16*)alloc((size_t)NBH * 32 * T_SEQ * 2);
    u16*   Ybuf   = (u16*)alloc((size_t)ROWS * 192 * 2);
    u16*   Part   = (u16*)alloc((size_t)4 * PART_SLOT * 2);

    u16* Qp = QpKp;
    u16* Kp = QpKp + (size_t)NBH * T_SEQ * 32;

    prep_wt<<<dim3((576 * 576 + 255) / 256), dim3(256), 0, stream>>>(Wq, Wk, Wv, Wo, WcT, WoSubT, cosT, sinT);

    // QKV projection: [8192,576(f32)] x [576,567(->576)] — XCD-aligned 1-D grid (64 m x 9 n)
    gemm_mfma<1, 0><<<dim3(64 * 9), dim3(256), 0, stream>>>((const void*)x, WcT, (void*)qkv, 576, 576, 576, 576);

    // merged rope + repack (vectorized loads; Q/K roped rows, V d-major transpose)
    repack_qkv<<<dim3(T_SEQ / 64, NBH), dim3(256), 0, stream>>>(qkv, cosT, sinT, Qp, Kp, Vp);

    // balanced split-K MFMA flash attention (128 q/block, 8 waves) + combine
    attn_mfma<<<dim3(40, NBH), dim3(512), 0, stream>>>(Qp, Kp, Vp, Ybuf, Part);
    attn_reduce<<<dim3(NBH * 1536 * 32 / 256), dim3(256), 0, stream>>>(Part, Ybuf);

    // output GEMM: [8192,192] x [192,576] — XCD-aligned 1-D grid (64 m x 9 n)
    gemm_mfma<0, 1><<<dim3(64 * 9), dim3(256), 0, stream>>>((const void*)Ybuf, WoSubT, (void*)out, 192, 192, 192, 576);
}

// Round 13
// 77.733 us; speedup vs baseline: 1.4174x; 1.0001x over previous
//
#include <hip/hip_runtime.h>
#include <hip/hip_bf16.h>

typedef unsigned short u16;
typedef unsigned int u32;
typedef __attribute__((ext_vector_type(8))) short bf16x8;
typedef __attribute__((ext_vector_type(4))) float f32x4;
typedef __attribute__((ext_vector_type(4))) int i32x4;

#define N_HEADS 9
#define T_SEQ 2048
#define BATCH 4
#define CDIM 576
#define ROWS (BATCH * T_SEQ) /* 8192 */
#define NBH (BATCH * N_HEADS) /* 36 */
#define PART_SLOT ((size_t)NBH * T_SEQ * 32) /* u16 elements per partial slot */

__device__ __forceinline__ u16 f2bf(float f) {
    u32 u = __float_as_uint(f);
    u32 r = u + 0x7FFFu + ((u >> 16) & 1u);
    return (u16)(r >> 16);
}
__device__ __forceinline__ float bf2f(u16 u) { return __uint_as_float(((u32)u) << 16); }
__device__ __forceinline__ u32 cvt_pk_bf16(float lo, float hi) {
    u32 r;
    asm("v_cvt_pk_bf16_f32 %0, %1, %2" : "=v"(r) : "v"(lo), "v"(hi));
    return r;
}
__device__ __forceinline__ float exp2_raw(float x) {
    float r;
    asm("v_exp_f32 %0, %1" : "=v"(r) : "v"(x));
    return r;
}

// ---------------- merged prep: weights + trig tables ----------------
__global__ __launch_bounds__(256) void prep_wt(const float* __restrict__ Wq, const float* __restrict__ Wk,
                                               const float* __restrict__ Wv, const float* __restrict__ Wo,
                                               u16* __restrict__ WcT, u16* __restrict__ WoSubT,
                                               float* __restrict__ cosT, float* __restrict__ sinT) {
    int idx = blockIdx.x * 256 + threadIdx.x;
    if (idx < 576 * 576) {
        int n = idx / 576, k = idx - n * 576;
        float v;
        if (n < 189)      v = Wq[(size_t)k * 576 + (n / 21) * 64 + (n % 21)];
        else if (n < 378) v = Wk[(size_t)k * 189 + (n - 189)];
        else if (n < 567) v = Wv[(size_t)k * 189 + (n - 378)];
        else              v = 0.f;
        WcT[(size_t)n * 576 + k] = f2bf(v);
    }
    if (idx < 576 * 192) {
        int n = idx / 192, k = idx - n * 192;
        float v = 0.f;
        if (k < 189) v = Wo[(size_t)((k / 21) * 64 + (k % 21)) * 576 + n];
        WoSubT[(size_t)n * 192 + k] = f2bf(v);
    }
    if (idx < T_SEQ * 21) {
        int t = idx / 21, d = idx - t * 21;
        int i = (d < 11) ? d : d - 11;
        float e = (2.0f * (float)i) / 21.0f;
        float invf = exp2f(-e * 13.287712379549449f); // 10000^-e
        float ang = (float)t * invf;
        cosT[idx] = cosf(ang);
        sinT[idx] = sinf(ang);
    }
}

// ---------------- bf16 MFMA GEMM: C[M,N] = A[M,K] * BT[N,K]^T ----------------
// 128x64 tile, 4 waves. 1-D grid, m = bx&63, n = bx>>6: blocks sharing an A panel land on
// the same XCD L2 -> A fetched from HBM once. AF32: A f32, converted in staging.

template <int AF32, int OUTF32>
__global__ __launch_bounds__(256) void gemm_mfma(const void* __restrict__ Av, const u16* __restrict__ BT,
                                                 void* __restrict__ Cout, int K, int lda, int ldbt, int ldc) {
    __shared__ u16 As[128][32];
    __shared__ u16 Bs[64][32];
    const int tid = threadIdx.x;
    const int lane = tid & 63, w = tid >> 6;
    const int m0 = (blockIdx.x & 63) * 128, n0 = (blockIdx.x >> 6) * 64;
    const int k15 = lane & 15, g = lane >> 4;

    const int arow = tid >> 1;          // 0..127
    const int ac0 = (tid & 1) * 2;      // chunks ac0, ac0+1
    const int brow = tid >> 2, bc = tid & 3;

    f32x4 zero = {0.f, 0.f, 0.f, 0.f};
    f32x4 acc[2][4];
#pragma unroll
    for (int hf = 0; hf < 2; hf++)
#pragma unroll
        for (int n = 0; n < 4; n++) acc[hf][n] = zero;

    const float* Af = (const float*)Av;
    const u16*   Ab = (const u16*)Av;

    float4 af0, af1, af2, af3;
    i32x4 av0, av1;
    if (AF32) {
        const float* ap = &Af[(size_t)(m0 + arow) * lda + ac0 * 8];
        af0 = *(const float4*)&ap[0];
        af1 = *(const float4*)&ap[4];
        af2 = *(const float4*)&ap[8];
        af3 = *(const float4*)&ap[12];
    } else {
        av0 = *(const i32x4*)&Ab[(size_t)(m0 + arow) * lda + ac0 * 8];
        av1 = *(const i32x4*)&Ab[(size_t)(m0 + arow) * lda + (ac0 + 1) * 8];
    }
    i32x4 bv = *(const i32x4*)&BT[(size_t)(n0 + brow) * ldbt + bc * 8];

    for (int k0 = 0; k0 < K; k0 += 32) {
        __syncthreads();
        if (AF32) {
            i32x4 w0, w1;
            w0[0] = (int)cvt_pk_bf16(af0.x, af0.y); w0[1] = (int)cvt_pk_bf16(af0.z, af0.w);
            w0[2] = (int)cvt_pk_bf16(af1.x, af1.y); w0[3] = (int)cvt_pk_bf16(af1.z, af1.w);
            w1[0] = (int)cvt_pk_bf16(af2.x, af2.y); w1[1] = (int)cvt_pk_bf16(af2.z, af2.w);
            w1[2] = (int)cvt_pk_bf16(af3.x, af3.y); w1[3] = (int)cvt_pk_bf16(af3.z, af3.w);
            *(i32x4*)&As[arow][(ac0 ^ (arow & 3)) * 8] = w0;
            *(i32x4*)&As[arow][((ac0 + 1) ^ (arow & 3)) * 8] = w1;
        } else {
            *(i32x4*)&As[arow][(ac0 ^ (arow & 3)) * 8] = av0;
            *(i32x4*)&As[arow][((ac0 + 1) ^ (arow & 3)) * 8] = av1;
        }
        *(i32x4*)&Bs[brow][(bc ^ (brow & 3)) * 8] = bv;
        __syncthreads();
        int k1 = k0 + 32;
        if (k1 < K) {
            if (AF32) {
                const float* ap = &Af[(size_t)(m0 + arow) * lda + k1 + ac0 * 8];
                af0 = *(const float4*)&ap[0];
                af1 = *(const float4*)&ap[4];
                af2 = *(const float4*)&ap[8];
                af3 = *(const float4*)&ap[12];
            } else {
                av0 = *(const i32x4*)&Ab[(size_t)(m0 + arow) * lda + k1 + ac0 * 8];
                av1 = *(const i32x4*)&Ab[(size_t)(m0 + arow) * lda + k1 + (ac0 + 1) * 8];
            }
            bv = *(const i32x4*)&BT[(size_t)(n0 + brow) * ldbt + k1 + bc * 8];
        }
        const int ar0 = w * 32 + k15;
        bf16x8 a0 = *(const bf16x8*)&As[ar0][(g ^ (ar0 & 3)) * 8];
        bf16x8 a1 = *(const bf16x8*)&As[ar0 + 16][(g ^ (ar0 & 3)) * 8];
#pragma unroll
        for (int n = 0; n < 4; n++) {
            int br = n * 16 + k15;
            bf16x8 b = *(const bf16x8*)&Bs[br][(g ^ (br & 3)) * 8];
            acc[0][n] = __builtin_amdgcn_mfma_f32_16x16x32_bf16(a0, b, acc[0][n], 0, 0, 0);
            acc[1][n] = __builtin_amdgcn_mfma_f32_16x16x32_bf16(a1, b, acc[1][n], 0, 0, 0);
        }
    }
#pragma unroll
    for (int hf = 0; hf < 2; hf++)
#pragma unroll
        for (int n = 0; n < 4; n++)
#pragma unroll
            for (int i = 0; i < 4; i++) {
                int row = m0 + w * 32 + hf * 16 + g * 4 + i;
                int col = n0 + n * 16 + k15;
                float v = acc[hf][n][i];
                if (OUTF32) ((float*)Cout)[(size_t)row * ldc + col] = v;
                else        ((u16*)Cout)[(size_t)row * ldc + col] = f2bf(v);
            }
}

// ---------------- merged repack: rope Q/K + V transpose, vectorized loads ----------------

__global__ __launch_bounds__(256) void repack_qkv(const u16* __restrict__ qkv,
                                                  const float* __restrict__ cosT,
                                                  const float* __restrict__ sinT,
                                                  u16* __restrict__ Qp, u16* __restrict__ Kp,
                                                  u16* __restrict__ Vp) {
    __shared__ u16 Qs[64][40];
    __shared__ u16 Ksh[64][40];
    __shared__ u16 Vsh[64][40];
    const int tid = threadIdx.x;
    const int bh = blockIdx.y;
    const int b = bh / N_HEADS, h = bh - b * N_HEADS;
    const int t0 = blockIdx.x * 64;

    const int qa = (h * 21) & ~7,        qoff = h * 21 - qa;
    const int ka = (189 + h * 21) & ~7,  koff = 189 + h * 21 - ka;
    const int va = (378 + h * 21) & ~7,  voff = 378 + h * 21 - va;

#pragma unroll
    for (int it = 0; it < 3; ++it) {
        int idx = tid + it * 256;  // 0..767
        int row = idx / 12;
        int r12 = idx - row * 12;
        int stream = r12 >> 2, chunk = r12 & 3;
        int off = (stream == 0) ? qa : (stream == 1) ? ka : va;
        const u16* src = qkv + (size_t)(b * T_SEQ + t0 + row) * CDIM + off + chunk * 8;
        i32x4 v = *(const i32x4*)src;
        u16* dst = (stream == 0) ? &Qs[row][0] : (stream == 1) ? &Ksh[row][0] : &Vsh[row][0];
        *(i32x4*)&dst[chunk * 8] = v;
    }
    __syncthreads();

    const int r = tid >> 2, c = tid & 3;
    const int t = t0 + r;
    const float* cr = cosT + t * 21;
    const float* sr = sinT + t * 21;
    u32 wq[4] = {0, 0, 0, 0}, wk[4] = {0, 0, 0, 0};
    const float sc = 0.18033688011112042f; // 0.125 * log2(e)
#pragma unroll
    for (int j = 0; j < 8; j++) {
        int d = c * 8 + j;
        float vq = 0.f, vk = 0.f;
        if (d < 21) {
            int pd = (d < 11) ? d + 10 : d - 11;
            float cc = cr[d], ss = sr[d];
            float qv = bf2f(Qs[r][qoff + d]),  qp = bf2f(Qs[r][qoff + pd]);
            float kv = bf2f(Ksh[r][koff + d]), kp = bf2f(Ksh[r][koff + pd]);
            float rq = (d < 11) ? -qp : qp;
            float rk = (d < 11) ? -kp : kp;
            vq = (qv * cc + rq * ss) * sc;
            vk = kv * cc + rk * ss;
        }
        wq[j >> 1] |= (u32)f2bf(vq) << ((j & 1) * 16);
        wk[j >> 1] |= (u32)f2bf(vk) << ((j & 1) * 16);
    }
    size_t obase = ((size_t)bh * T_SEQ + t) * 32 + c * 8;
    i32x4 q4; q4[0] = (int)wq[0]; q4[1] = (int)wq[1]; q4[2] = (int)wq[2]; q4[3] = (int)wq[3];
    i32x4 k4; k4[0] = (int)wk[0]; k4[1] = (int)wk[1]; k4[2] = (int)wk[2]; k4[3] = (int)wk[3];
    *(i32x4*)&Qp[obase] = q4;
    *(i32x4*)&Kp[obase] = k4;

    const int dv = tid >> 3, tc = tid & 7;
    u32 wv[4];
#pragma unroll
    for (int j = 0; j < 4; j++) {
        u16 lo, hi;
        if (dv < 21)      { lo = Vsh[tc * 8 + j * 2][voff + dv]; hi = Vsh[tc * 8 + j * 2 + 1][voff + dv]; }
        else if (dv == 31){ lo = 0x3F80; hi = 0x3F80; }
        else              { lo = 0; hi = 0; }
        wv[j] = (u32)lo | ((u32)hi << 16);
    }
    i32x4 v4; v4[0] = (int)wv[0]; v4[1] = (int)wv[1]; v4[2] = (int)wv[2]; v4[3] = (int)wv[3];
    *(i32x4*)&Vp[((size_t)bh * 32 + dv) * T_SEQ + t0 + tc * 8] = v4;
}

// ---------------- split-K MFMA flash attention: 128 q-rows/block, 8 waves ----------------
// Fixed-base softmax (bounded scores) => linear in keys => split-K partials.
// One staged 128-key unit now feeds 8 waves (128 q) => staging bytes & barriers per score
// halved vs 64-q blocks. Wave w owns q rows q0+w*16..+15; its diagonal key-tile is
// kd = 2*qt2 + (w>>2); waves skip tiles beyond kd. nc = (qt2>>2)+1 chunks (<=4 slots).

__global__ __launch_bounds__(512) void attn_mfma(const u16* __restrict__ Qp,
                                                 const u16* __restrict__ Kp,
                                                 const u16* __restrict__ Vp,
                                                 u16* __restrict__ Ybuf,
                                                 u16* __restrict__ Part) {
    __shared__ u16 Ks[128][40];       // 80B rows
    __shared__ u16 Vt[32][136];       // 272B rows
    __shared__ u16 Pt[2][8][16][72];  // [sub][wave][q][key]
    const int tid = threadIdx.x;
    const int lane = tid & 63, w = tid >> 6;   // w 0..7
    const int bh = blockIdx.y;
    const int b = bh / N_HEADS, h = bh - b * N_HEADS;
    const int k15 = lane & 15, g = lane >> 4;

    // bx -> (qt2, ci), heavy q-tiles first. nc(qt2) = (qt2>>2)+1, sum = 40.
    int qt2 = 15, ci = blockIdx.x;
    for (int q = 15; q >= 0; --q) {
        int n = (q >> 2) + 1;
        if (ci < n) { qt2 = q; break; }
        ci -= n;
    }
    const int q0 = qt2 * 128;
    const int n128 = qt2 + 1;            // 128-key units covering keys 0..q0+127
    const int nc = (qt2 >> 2) + 1;
    const int u_begin = (ci * n128) / nc;
    const int u_end = ((ci + 1) * n128) / nc;

    // staging: threads 0..255 stage K (128x32), 256..511 stage V (32x128); 2x16B each
    const bool isK = (tid < 256);
    const int krow = (tid & 255) >> 2, kc = tid & 3;       // K: rows krow, krow+64
    const int vrow = (tid & 255) >> 3, vc = tid & 7;       // V: chunks vc, vc+8
    const u16* Kg = Kp + (size_t)bh * 65536 + krow * 32 + kc * 8;
    const u16* Vg = Vp + (size_t)bh * 65536 + vrow * 2048 + vc * 8;

    // Q B-fragment held in regs: B[n=q][k=d]
    bf16x8 qf = *(const bf16x8*)&Qp[(((size_t)bh << 11) + q0 + w * 16 + k15) * 32 + g * 8];

    f32x4 y0 = {0.f, 0.f, 0.f, 0.f}, y1 = {0.f, 0.f, 0.f, 0.f};
    const int qloc = (w & 3) * 16 + k15;       // q position within its 64-aligned block
    const int kd = 2 * qt2 + (w >> 2);         // wave's diagonal 64-key tile index

    // prologue loads (unit u_begin)
    u32 off = (u32)u_begin * 4096u;            // K: u16 elems per unit (128*32)
    u32 voffu = (u32)u_begin * 128u;           // V: u16 elems per unit per row
    i32x4 r0, r1;
    if (isK) { r0 = *(const i32x4*)&Kg[off];   r1 = *(const i32x4*)&Kg[off + 2048]; }
    else     { r0 = *(const i32x4*)&Vg[voffu]; r1 = *(const i32x4*)&Vg[voffu + 64]; }

    for (int u = u_begin; u < u_end; ++u) {
        __syncthreads();                       // prior compute done with LDS
        if (isK) {
            *(i32x4*)&Ks[krow][kc * 8] = r0;
            *(i32x4*)&Ks[krow + 64][kc * 8] = r1;
        } else {
            *(i32x4*)&Vt[vrow][vc * 8] = r0;
            *(i32x4*)&Vt[vrow][vc * 8 + 64] = r1;
        }
        if (u + 1 < u_end) {                   // prefetch next unit (overlaps compute)
            off += 4096u; voffu += 128u;
            if (isK) { r0 = *(const i32x4*)&Kg[off];   r1 = *(const i32x4*)&Kg[off + 2048]; }
            else     { r0 = *(const i32x4*)&Vg[voffu]; r1 = *(const i32x4*)&Vg[voffu + 64]; }
        }
        __syncthreads();                       // LDS ready

        const int kt0 = u * 2;
        const bool do0 = (kt0 <= kd);
        const bool do1 = (kt0 + 1 <= kd);

        f32x4 s0[4], s1[4];
        if (do0) {
#pragma unroll
            for (int f = 0; f < 4; f++) {
                bf16x8 kf = *(const bf16x8*)&Ks[f * 16 + k15][g * 8];
                f32x4 z = {0.f, 0.f, 0.f, 0.f};
                s0[f] = __builtin_amdgcn_mfma_f32_16x16x32_bf16(kf, qf, z, 0, 0, 0);
            }
        }
        if (do1) {
#pragma unroll
            for (int f = 0; f < 4; f++) {
                bf16x8 kf = *(const bf16x8*)&Ks[64 + f * 16 + k15][g * 8];
                f32x4 z = {0.f, 0.f, 0.f, 0.f};
                s1[f] = __builtin_amdgcn_mfma_f32_16x16x32_bf16(kf, qf, z, 0, 0, 0);
            }
        }
        if (do0 && kt0 == kd) {
#pragma unroll
            for (int f = 0; f < 4; f++)
#pragma unroll
                for (int i = 0; i < 4; i++)
                    if (f * 16 + g * 4 + i > qloc) s0[f][i] = -16384.f;
        }
        if (do1 && kt0 + 1 == kd) {
#pragma unroll
            for (int f = 0; f < 4; f++)
#pragma unroll
                for (int i = 0; i < 4; i++)
                    if (f * 16 + g * 4 + i > qloc) s1[f][i] = -16384.f;
        }

        if (do0) {
#pragma unroll
            for (int f = 0; f < 4; f++) {
                u32 lo = cvt_pk_bf16(exp2_raw(s0[f][0]), exp2_raw(s0[f][1]));
                u32 hi = cvt_pk_bf16(exp2_raw(s0[f][2]), exp2_raw(s0[f][3]));
                uint2 pk; pk.x = lo; pk.y = hi;
                *(uint2*)&Pt[0][w][k15][f * 16 + g * 4] = pk;
            }
        }
        if (do1) {
#pragma unroll
            for (int f = 0; f < 4; f++) {
                u32 lo = cvt_pk_bf16(exp2_raw(s1[f][0]), exp2_raw(s1[f][1]));
                u32 hi = cvt_pk_bf16(exp2_raw(s1[f][2]), exp2_raw(s1[f][3]));
                uint2 pk; pk.x = lo; pk.y = hi;
                *(uint2*)&Pt[1][w][k15][f * 16 + g * 4] = pk;
            }
        }
        asm volatile("" ::: "memory"); // Pt writes ordered before reads (wave-local)

        if (do0) {
#pragma unroll
            for (int kh = 0; kh < 2; kh++) {
                bf16x8 pa = *(const bf16x8*)&Pt[0][w][k15][kh * 32 + g * 8];
                bf16x8 v0 = *(const bf16x8*)&Vt[k15][kh * 32 + g * 8];
                bf16x8 v1 = *(const bf16x8*)&Vt[16 + k15][kh * 32 + g * 8];
                y0 = __builtin_amdgcn_mfma_f32_16x16x32_bf16(pa, v0, y0, 0, 0, 0);
                y1 = __builtin_amdgcn_mfma_f32_16x16x32_bf16(pa, v1, y1, 0, 0, 0);
            }
        }
        if (do1) {
#pragma unroll
            for (int kh = 0; kh < 2; kh++) {
                bf16x8 pa = *(const bf16x8*)&Pt[1][w][k15][kh * 32 + g * 8];
                bf16x8 v0 = *(const bf16x8*)&Vt[k15][64 + kh * 32 + g * 8];
                bf16x8 v1 = *(const bf16x8*)&Vt[16 + k15][64 + kh * 32 + g * 8];
                y0 = __builtin_amdgcn_mfma_f32_16x16x32_bf16(pa, v0, y0, 0, 0, 0);
                y1 = __builtin_amdgcn_mfma_f32_16x16x32_bf16(pa, v1, y1, 0, 0, 0);
            }
        }
        asm volatile("" ::: "memory"); // Pt reads done before next unit's writes
    }

    if (nc == 1) { // qt2 < 4: single chunk, normalize by l (= y1 col 15 ones-column), write
#pragma unroll
        for (int i = 0; i < 4; i++) {
            float li = __shfl(y1[i], (lane & 48) + 15);
            float inv = 1.0f / li;
            int rowY = b * T_SEQ + q0 + w * 16 + g * 4 + i;
            u16* yr = &Ybuf[(size_t)rowY * 192 + h * 21];
            yr[k15] = f2bf(y0[i] * inv);
            if (k15 < 5) yr[16 + k15] = f2bf(y1[i] * inv);
        }
    } else { // bf16 partials (denominator at d=31)
#pragma unroll
        for (int i = 0; i < 4; i++) {
            size_t pb = (size_t)ci * PART_SLOT +
                        (((size_t)bh << 11) + q0 + w * 16 + g * 4 + i) * 32;
            Part[pb + k15] = f2bf(y0[i]);
            Part[pb + 16 + k15] = f2bf(y1[i]);
        }
    }
}

// combine nc partial slots for rows t >= 512, normalize, write Ybuf. nc = (t>>9)+1.
__global__ __launch_bounds__(256) void attn_reduce(const u16* __restrict__ Part, u16* __restrict__ Ybuf) {
    int gid = blockIdx.x * 256 + threadIdx.x; // 36 * 1536 * 32
    int d = gid & 31;
    int rest = gid >> 5;
    int t = 512 + (rest % 1536);
    int bh = rest / 1536;
    int b = bh / N_HEADS, h = bh - b * N_HEADS;
    int nc = (t >> 9) + 1;
    size_t base = (((size_t)bh << 11) + t) * 32;
    float l = 0.f, v = 0.f;
    for (int ci = 0; ci < nc; ci++) {
        l += bf2f(Part[(size_t)ci * PART_SLOT + base + 31]);
        if (d < 21) v += bf2f(Part[(size_t)ci * PART_SLOT + base + d]);
    }
    if (d < 21) Ybuf[(size_t)(b * T_SEQ + t) * 192 + h * 21 + d] = f2bf(v / l);
}

// ---------------- launch ----------------

extern "C" void kernel_launch(void* const* d_in, const int* in_sizes, int n_in,
                              void* d_out, int out_size, void* d_ws, size_t ws_size,
                              hipStream_t stream) {
    const float* x  = (const float*)d_in[0];
    const float* Wq = (const float*)d_in[1];
    const float* Wk = (const float*)d_in[2];
    const float* Wv = (const float*)d_in[3];
    const float* Wo = (const float*)d_in[4];
    float* out = (float*)d_out;

    char* p = (char*)d_ws;
    auto alloc = [&](size_t bytes) { char* r = p; p += (bytes + 255) & ~(size_t)255; return r; };
    u16*   QpKp   = (u16*)alloc((size_t)ROWS * CDIM * 2);   // Qp | Kp
    u16*   qkv    = (u16*)alloc((size_t)ROWS * CDIM * 2);
    u16*   WcT    = (u16*)alloc((size_t)576 * 576 * 2);
    u16*   WoSubT = (u16*)alloc((size_t)576 * 192 * 2);
    float* cosT   = (float*)alloc((size_t)T_SEQ * 21 * 4);
    float* sinT   = (float*)alloc((size_t)T_SEQ * 21 * 4);
    u16*   Vp     = (u16*)alloc((size_t)NBH * 32 * T_SEQ * 2);
    u16*   Ybuf   = (u16*)alloc((size_t)ROWS * 192 * 2);
    u16*   Part   = (u16*)alloc((size_t)4 * PART_SLOT * 2);

    u16* Qp = QpKp;
    u16* Kp = QpKp + (size_t)NBH * T_SEQ * 32;

    prep_wt<<<dim3((576 * 576 + 255) / 256), dim3(256), 0, stream>>>(Wq, Wk, Wv, Wo, WcT, WoSubT, cosT, sinT);

    // QKV projection: [8192,576(f32)] x [576,567(->576)] — XCD-aligned 1-D grid (64 m x 9 n)
    gemm_mfma<1, 0><<<dim3(64 * 9), dim3(256), 0, stream>>>((const void*)x, WcT, (void*)qkv, 576, 576, 576, 576);

    // merged rope + repack (vectorized loads; Q/K roped rows, V d-major transpose)
    repack_qkv<<<dim3(T_SEQ / 64, NBH), dim3(256), 0, stream>>>(qkv, cosT, sinT, Qp, Kp, Vp);

    // balanced split-K MFMA flash attention (128 q/block, 8 waves) + combine
    attn_mfma<<<dim3(40, NBH), dim3(512), 0, stream>>>(Qp, Kp, Vp, Ybuf, Part);
    attn_reduce<<<dim3(NBH * 1536 * 32 / 256), dim3(256), 0, stream>>>(Part, Ybuf);

    // output GEMM: [8192,192] x [192,576] — XCD-aligned 1-D grid (64 m x 9 n)
    gemm_mfma<0, 1><<<dim3(64 * 9), dim3(256), 0, stream>>>((const void*)Ybuf, WoSubT, (void*)out, 192, 192, 192, 576);
}

// Round 14
// 77.689 us; speedup vs baseline: 1.4182x; 1.0006x over previous
//
#include <hip/hip_runtime.h>
#include <hip/hip_bf16.h>

typedef unsigned short u16;
typedef unsigned int u32;
typedef __attribute__((ext_vector_type(8))) short bf16x8;
typedef __attribute__((ext_vector_type(4))) float f32x4;
typedef __attribute__((ext_vector_type(4))) int i32x4;

#define N_HEADS 9
#define T_SEQ 2048
#define BATCH 4
#define CDIM 576
#define ROWS (BATCH * T_SEQ) /* 8192 */
#define NBH (BATCH * N_HEADS) /* 36 */
#define PART_SLOT ((size_t)NBH * T_SEQ * 32) /* u16 elements per partial slot */

__device__ __forceinline__ u16 f2bf(float f) {
    u32 u = __float_as_uint(f);
    u32 r = u + 0x7FFFu + ((u >> 16) & 1u);
    return (u16)(r >> 16);
}
__device__ __forceinline__ float bf2f(u16 u) { return __uint_as_float(((u32)u) << 16); }
__device__ __forceinline__ u32 cvt_pk_bf16(float lo, float hi) {
    u32 r;
    asm("v_cvt_pk_bf16_f32 %0, %1, %2" : "=v"(r) : "v"(lo), "v"(hi));
    return r;
}
__device__ __forceinline__ float exp2_raw(float x) {
    float r;
    asm("v_exp_f32 %0, %1" : "=v"(r) : "v"(x));
    return r;
}

// ---------------- merged prep: weights + trig tables ----------------
__global__ __launch_bounds__(256) void prep_wt(const float* __restrict__ Wq, const float* __restrict__ Wk,
                                               const float* __restrict__ Wv, const float* __restrict__ Wo,
                                               u16* __restrict__ WcT, u16* __restrict__ WoSubT,
                                               float* __restrict__ cosT, float* __restrict__ sinT) {
    int idx = blockIdx.x * 256 + threadIdx.x;
    if (idx < 576 * 576) {
        int n = idx / 576, k = idx - n * 576;
        float v;
        if (n < 189)      v = Wq[(size_t)k * 576 + (n / 21) * 64 + (n % 21)];
        else if (n < 378) v = Wk[(size_t)k * 189 + (n - 189)];
        else if (n < 567) v = Wv[(size_t)k * 189 + (n - 378)];
        else              v = 0.f;
        WcT[(size_t)n * 576 + k] = f2bf(v);
    }
    if (idx < 576 * 192) {
        int n = idx / 192, k = idx - n * 192;
        float v = 0.f;
        if (k < 189) v = Wo[(size_t)((k / 21) * 64 + (k % 21)) * 576 + n];
        WoSubT[(size_t)n * 192 + k] = f2bf(v);
    }
    if (idx < T_SEQ * 21) {
        int t = idx / 21, d = idx - t * 21;
        int i = (d < 11) ? d : d - 11;
        float e = (2.0f * (float)i) / 21.0f;
        float invf = exp2f(-e * 13.287712379549449f); // 10000^-e
        float ang = (float)t * invf;
        cosT[idx] = cosf(ang);
        sinT[idx] = sinf(ang);
    }
}

// ---------------- bf16 MFMA GEMM: C[M,N] = A[M,K] * BT[N,K]^T ----------------
// 128x64 tile, 4 waves. 1-D grid, m = bx&63, n = bx>>6: blocks sharing an A panel land on
// the same XCD L2 -> A fetched from HBM once. AF32: A f32, converted in staging.

template <int AF32, int OUTF32>
__global__ __launch_bounds__(256) void gemm_mfma(const void* __restrict__ Av, const u16* __restrict__ BT,
                                                 void* __restrict__ Cout, int K, int lda, int ldbt, int ldc) {
    __shared__ u16 As[128][32];
    __shared__ u16 Bs[64][32];
    const int tid = threadIdx.x;
    const int lane = tid & 63, w = tid >> 6;
    const int m0 = (blockIdx.x & 63) * 128, n0 = (blockIdx.x >> 6) * 64;
    const int k15 = lane & 15, g = lane >> 4;

    const int arow = tid >> 1;          // 0..127
    const int ac0 = (tid & 1) * 2;      // chunks ac0, ac0+1
    const int brow = tid >> 2, bc = tid & 3;

    f32x4 zero = {0.f, 0.f, 0.f, 0.f};
    f32x4 acc[2][4];
#pragma unroll
    for (int hf = 0; hf < 2; hf++)
#pragma unroll
        for (int n = 0; n < 4; n++) acc[hf][n] = zero;

    const float* Af = (const float*)Av;
    const u16*   Ab = (const u16*)Av;

    float4 af0, af1, af2, af3;
    i32x4 av0, av1;
    if (AF32) {
        const float* ap = &Af[(size_t)(m0 + arow) * lda + ac0 * 8];
        af0 = *(const float4*)&ap[0];
        af1 = *(const float4*)&ap[4];
        af2 = *(const float4*)&ap[8];
        af3 = *(const float4*)&ap[12];
    } else {
        av0 = *(const i32x4*)&Ab[(size_t)(m0 + arow) * lda + ac0 * 8];
        av1 = *(const i32x4*)&Ab[(size_t)(m0 + arow) * lda + (ac0 + 1) * 8];
    }
    i32x4 bv = *(const i32x4*)&BT[(size_t)(n0 + brow) * ldbt + bc * 8];

    for (int k0 = 0; k0 < K; k0 += 32) {
        __syncthreads();
        if (AF32) {
            i32x4 w0, w1;
            w0[0] = (int)cvt_pk_bf16(af0.x, af0.y); w0[1] = (int)cvt_pk_bf16(af0.z, af0.w);
            w0[2] = (int)cvt_pk_bf16(af1.x, af1.y); w0[3] = (int)cvt_pk_bf16(af1.z, af1.w);
            w1[0] = (int)cvt_pk_bf16(af2.x, af2.y); w1[1] = (int)cvt_pk_bf16(af2.z, af2.w);
            w1[2] = (int)cvt_pk_bf16(af3.x, af3.y); w1[3] = (int)cvt_pk_bf16(af3.z, af3.w);
            *(i32x4*)&As[arow][(ac0 ^ (arow & 3)) * 8] = w0;
            *(i32x4*)&As[arow][((ac0 + 1) ^ (arow & 3)) * 8] = w1;
        } else {
            *(i32x4*)&As[arow][(ac0 ^ (arow & 3)) * 8] = av0;
            *(i32x4*)&As[arow][((ac0 + 1) ^ (arow & 3)) * 8] = av1;
        }
        *(i32x4*)&Bs[brow][(bc ^ (brow & 3)) * 8] = bv;
        __syncthreads();
        int k1 = k0 + 32;
        if (k1 < K) {
            if (AF32) {
                const float* ap = &Af[(size_t)(m0 + arow) * lda + k1 + ac0 * 8];
                af0 = *(const float4*)&ap[0];
                af1 = *(const float4*)&ap[4];
                af2 = *(const float4*)&ap[8];
                af3 = *(const float4*)&ap[12];
            } else {
                av0 = *(const i32x4*)&Ab[(size_t)(m0 + arow) * lda + k1 + ac0 * 8];
                av1 = *(const i32x4*)&Ab[(size_t)(m0 + arow) * lda + k1 + (ac0 + 1) * 8];
            }
            bv = *(const i32x4*)&BT[(size_t)(n0 + brow) * ldbt + k1 + bc * 8];
        }
        const int ar0 = w * 32 + k15;
        bf16x8 a0 = *(const bf16x8*)&As[ar0][(g ^ (ar0 & 3)) * 8];
        bf16x8 a1 = *(const bf16x8*)&As[ar0 + 16][(g ^ (ar0 & 3)) * 8];
#pragma unroll
        for (int n = 0; n < 4; n++) {
            int br = n * 16 + k15;
            bf16x8 b = *(const bf16x8*)&Bs[br][(g ^ (br & 3)) * 8];
            acc[0][n] = __builtin_amdgcn_mfma_f32_16x16x32_bf16(a0, b, acc[0][n], 0, 0, 0);
            acc[1][n] = __builtin_amdgcn_mfma_f32_16x16x32_bf16(a1, b, acc[1][n], 0, 0, 0);
        }
    }
#pragma unroll
    for (int hf = 0; hf < 2; hf++)
#pragma unroll
        for (int n = 0; n < 4; n++)
#pragma unroll
            for (int i = 0; i < 4; i++) {
                int row = m0 + w * 32 + hf * 16 + g * 4 + i;
                int col = n0 + n * 16 + k15;
                float v = acc[hf][n][i];
                if (OUTF32) ((float*)Cout)[(size_t)row * ldc + col] = v;
                else        ((u16*)Cout)[(size_t)row * ldc + col] = f2bf(v);
            }
}

// ---------------- merged repack: rope Q/K + V transpose, vectorized loads ----------------

__global__ __launch_bounds__(256) void repack_qkv(const u16* __restrict__ qkv,
                                                  const float* __restrict__ cosT,
                                                  const float* __restrict__ sinT,
                                                  u16* __restrict__ Qp, u16* __restrict__ Kp,
                                                  u16* __restrict__ Vp) {
    __shared__ u16 Qs[64][40];
    __shared__ u16 Ksh[64][40];
    __shared__ u16 Vsh[64][40];
    const int tid = threadIdx.x;
    const int bh = blockIdx.y;
    const int b = bh / N_HEADS, h = bh - b * N_HEADS;
    const int t0 = blockIdx.x * 64;

    const int qa = (h * 21) & ~7,        qoff = h * 21 - qa;
    const int ka = (189 + h * 21) & ~7,  koff = 189 + h * 21 - ka;
    const int va = (378 + h * 21) & ~7,  voff = 378 + h * 21 - va;

#pragma unroll
    for (int it = 0; it < 3; ++it) {
        int idx = tid + it * 256;  // 0..767
        int row = idx / 12;
        int r12 = idx - row * 12;
        int stream = r12 >> 2, chunk = r12 & 3;
        int off = (stream == 0) ? qa : (stream == 1) ? ka : va;
        const u16* src = qkv + (size_t)(b * T_SEQ + t0 + row) * CDIM + off + chunk * 8;
        i32x4 v = *(const i32x4*)src;
        u16* dst = (stream == 0) ? &Qs[row][0] : (stream == 1) ? &Ksh[row][0] : &Vsh[row][0];
        *(i32x4*)&dst[chunk * 8] = v;
    }
    __syncthreads();

    const int r = tid >> 2, c = tid & 3;
    const int t = t0 + r;
    const float* cr = cosT + t * 21;
    const float* sr = sinT + t * 21;
    u32 wq[4] = {0, 0, 0, 0}, wk[4] = {0, 0, 0, 0};
    const float sc = 0.18033688011112042f; // 0.125 * log2(e)
#pragma unroll
    for (int j = 0; j < 8; j++) {
        int d = c * 8 + j;
        float vq = 0.f, vk = 0.f;
        if (d < 21) {
            int pd = (d < 11) ? d + 10 : d - 11;
            float cc = cr[d], ss = sr[d];
            float qv = bf2f(Qs[r][qoff + d]),  qp = bf2f(Qs[r][qoff + pd]);
            float kv = bf2f(Ksh[r][koff + d]), kp = bf2f(Ksh[r][koff + pd]);
            float rq = (d < 11) ? -qp : qp;
            float rk = (d < 11) ? -kp : kp;
            vq = (qv * cc + rq * ss) * sc;
            vk = kv * cc + rk * ss;
        }
        wq[j >> 1] |= (u32)f2bf(vq) << ((j & 1) * 16);
        wk[j >> 1] |= (u32)f2bf(vk) << ((j & 1) * 16);
    }
    size_t obase = ((size_t)bh * T_SEQ + t) * 32 + c * 8;
    i32x4 q4; q4[0] = (int)wq[0]; q4[1] = (int)wq[1]; q4[2] = (int)wq[2]; q4[3] = (int)wq[3];
    i32x4 k4; k4[0] = (int)wk[0]; k4[1] = (int)wk[1]; k4[2] = (int)wk[2]; k4[3] = (int)wk[3];
    *(i32x4*)&Qp[obase] = q4;
    *(i32x4*)&Kp[obase] = k4;

    const int dv = tid >> 3, tc = tid & 7;
    u32 wv[4];
#pragma unroll
    for (int j = 0; j < 4; j++) {
        u16 lo, hi;
        if (dv < 21)      { lo = Vsh[tc * 8 + j * 2][voff + dv]; hi = Vsh[tc * 8 + j * 2 + 1][voff + dv]; }
        else if (dv == 31){ lo = 0x3F80; hi = 0x3F80; }
        else              { lo = 0; hi = 0; }
        wv[j] = (u32)lo | ((u32)hi << 16);
    }
    i32x4 v4; v4[0] = (int)wv[0]; v4[1] = (int)wv[1]; v4[2] = (int)wv[2]; v4[3] = (int)wv[3];
    *(i32x4*)&Vp[((size_t)bh * 32 + dv) * T_SEQ + t0 + tc * 8] = v4;
}

// ---------------- split-K MFMA flash attention: 128 q-rows/block, 8 waves ----------------
// Fixed-base softmax (bounded scores) => linear in keys => split-K partials.
// One staged 128-key unit now feeds 8 waves (128 q) => staging bytes & barriers per score
// halved vs 64-q blocks. Wave w owns q rows q0+w*16..+15; its diagonal key-tile is
// kd = 2*qt2 + (w>>2); waves skip tiles beyond kd. nc = (qt2>>2)+1 chunks (<=4 slots).

__global__ __launch_bounds__(512) void attn_mfma(const u16* __restrict__ Qp,
                                                 const u16* __restrict__ Kp,
                                                 const u16* __restrict__ Vp,
                                                 u16* __restrict__ Ybuf,
                                                 u16* __restrict__ Part) {
    __shared__ u16 Ks[128][40];       // 80B rows
    __shared__ u16 Vt[32][136];       // 272B rows
    __shared__ u16 Pt[2][8][16][72];  // [sub][wave][q][key]
    const int tid = threadIdx.x;
    const int lane = tid & 63, w = tid >> 6;   // w 0..7
    const int bh = blockIdx.y;
    const int b = bh / N_HEADS, h = bh - b * N_HEADS;
    const int k15 = lane & 15, g = lane >> 4;

    // bx -> (qt2, ci), heavy q-tiles first. nc(qt2) = (qt2>>2)+1, sum = 40.
    int qt2 = 15, ci = blockIdx.x;
    for (int q = 15; q >= 0; --q) {
        int n = (q >> 2) + 1;
        if (ci < n) { qt2 = q; break; }
        ci -= n;
    }
    const int q0 = qt2 * 128;
    const int n128 = qt2 + 1;            // 128-key units covering keys 0..q0+127
    const int nc = (qt2 >> 2) + 1;
    const int u_begin = (ci * n128) / nc;
    const int u_end = ((ci + 1) * n128) / nc;

    // staging: threads 0..255 stage K (128x32), 256..511 stage V (32x128); 2x16B each
    const bool isK = (tid < 256);
    const int krow = (tid & 255) >> 2, kc = tid & 3;       // K: rows krow, krow+64
    const int vrow = (tid & 255) >> 3, vc = tid & 7;       // V: chunks vc, vc+8
    const u16* Kg = Kp + (size_t)bh * 65536 + krow * 32 + kc * 8;
    const u16* Vg = Vp + (size_t)bh * 65536 + vrow * 2048 + vc * 8;

    // Q B-fragment held in regs: B[n=q][k=d]
    bf16x8 qf = *(const bf16x8*)&Qp[(((size_t)bh << 11) + q0 + w * 16 + k15) * 32 + g * 8];

    f32x4 y0 = {0.f, 0.f, 0.f, 0.f}, y1 = {0.f, 0.f, 0.f, 0.f};
    const int qloc = (w & 3) * 16 + k15;       // q position within its 64-aligned block
    const int kd = 2 * qt2 + (w >> 2);         // wave's diagonal 64-key tile index

    // prologue loads (unit u_begin)
    u32 off = (u32)u_begin * 4096u;            // K: u16 elems per unit (128*32)
    u32 voffu = (u32)u_begin * 128u;           // V: u16 elems per unit per row
    i32x4 r0, r1;
    if (isK) { r0 = *(const i32x4*)&Kg[off];   r1 = *(const i32x4*)&Kg[off + 2048]; }
    else     { r0 = *(const i32x4*)&Vg[voffu]; r1 = *(const i32x4*)&Vg[voffu + 64]; }

    for (int u = u_begin; u < u_end; ++u) {
        __syncthreads();                       // prior compute done with LDS
        if (isK) {
            *(i32x4*)&Ks[krow][kc * 8] = r0;
            *(i32x4*)&Ks[krow + 64][kc * 8] = r1;
        } else {
            *(i32x4*)&Vt[vrow][vc * 8] = r0;
            *(i32x4*)&Vt[vrow][vc * 8 + 64] = r1;
        }
        if (u + 1 < u_end) {                   // prefetch next unit (overlaps compute)
            off += 4096u; voffu += 128u;
            if (isK) { r0 = *(const i32x4*)&Kg[off];   r1 = *(const i32x4*)&Kg[off + 2048]; }
            else     { r0 = *(const i32x4*)&Vg[voffu]; r1 = *(const i32x4*)&Vg[voffu + 64]; }
        }
        __syncthreads();                       // LDS ready

        const int kt0 = u * 2;
        const bool do0 = (kt0 <= kd);
        const bool do1 = (kt0 + 1 <= kd);

        f32x4 s0[4], s1[4];
        if (do0) {
#pragma unroll
            for (int f = 0; f < 4; f++) {
                bf16x8 kf = *(const bf16x8*)&Ks[f * 16 + k15][g * 8];
                f32x4 z = {0.f, 0.f, 0.f, 0.f};
                s0[f] = __builtin_amdgcn_mfma_f32_16x16x32_bf16(kf, qf, z, 0, 0, 0);
            }
        }
        if (do1) {
#pragma unroll
            for (int f = 0; f < 4; f++) {
                bf16x8 kf = *(const bf16x8*)&Ks[64 + f * 16 + k15][g * 8];
                f32x4 z = {0.f, 0.f, 0.f, 0.f};
                s1[f] = __builtin_amdgcn_mfma_f32_16x16x32_bf16(kf, qf, z, 0, 0, 0);
            }
        }
        if (do0 && kt0 == kd) {
#pragma unroll
            for (int f = 0; f < 4; f++)
#pragma unroll
                for (int i = 0; i < 4; i++)
                    if (f * 16 + g * 4 + i > qloc) s0[f][i] = -16384.f;
        }
        if (do1 && kt0 + 1 == kd) {
#pragma unroll
            for (int f = 0; f < 4; f++)
#pragma unroll
                for (int i = 0; i < 4; i++)
                    if (f * 16 + g * 4 + i > qloc) s1[f][i] = -16384.f;
        }

        if (do0) {
#pragma unroll
            for (int f = 0; f < 4; f++) {
                u32 lo = cvt_pk_bf16(exp2_raw(s0[f][0]), exp2_raw(s0[f][1]));
                u32 hi = cvt_pk_bf16(exp2_raw(s0[f][2]), exp2_raw(s0[f][3]));
                uint2 pk; pk.x = lo; pk.y = hi;
                *(uint2*)&Pt[0][w][k15][f * 16 + g * 4] = pk;
            }
        }
        if (do1) {
#pragma unroll
            for (int f = 0; f < 4; f++) {
                u32 lo = cvt_pk_bf16(exp2_raw(s1[f][0]), exp2_raw(s1[f][1]));
                u32 hi = cvt_pk_bf16(exp2_raw(s1[f][2]), exp2_raw(s1[f][3]));
                uint2 pk; pk.x = lo; pk.y = hi;
                *(uint2*)&Pt[1][w][k15][f * 16 + g * 4] = pk;
            }
        }
        asm volatile("" ::: "memory"); // Pt writes ordered before reads (wave-local)

        if (do0) {
#pragma unroll
            for (int kh = 0; kh < 2; kh++) {
                bf16x8 pa = *(const bf16x8*)&Pt[0][w][k15][kh * 32 + g * 8];
                bf16x8 v0 = *(const bf16x8*)&Vt[k15][kh * 32 + g * 8];
                bf16x8 v1 = *(const bf16x8*)&Vt[16 + k15][kh * 32 + g * 8];
                y0 = __builtin_amdgcn_mfma_f32_16x16x32_bf16(pa, v0, y0, 0, 0, 0);
                y1 = __builtin_amdgcn_mfma_f32_16x16x32_bf16(pa, v1, y1, 0, 0, 0);
            }
        }
        if (do1) {
#pragma unroll
            for (int kh = 0; kh < 2; kh++) {
                bf16x8 pa = *(const bf16x8*)&Pt[1][w][k15][kh * 32 + g * 8];
                bf16x8 v0 = *(const bf16x8*)&Vt[k15][64 + kh * 32 + g * 8];
                bf16x8 v1 = *(const bf16x8*)&Vt[16 + k15][64 + kh * 32 + g * 8];
                y0 = __builtin_amdgcn_mfma_f32_16x16x32_bf16(pa, v0, y0, 0, 0, 0);
                y1 = __builtin_amdgcn_mfma_f32_16x16x32_bf16(pa, v1, y1, 0, 0, 0);
            }
        }
        asm volatile("" ::: "memory"); // Pt reads done before next unit's writes
    }

    if (nc == 1) { // qt2 < 4: single chunk, normalize by l (= y1 col 15 ones-column), write
#pragma unroll
        for (int i = 0; i < 4; i++) {
            float li = __shfl(y1[i], (lane & 48) + 15);
            float inv = 1.0f / li;
            int rowY = b * T_SEQ + q0 + w * 16 + g * 4 + i;
            u16* yr = &Ybuf[(size_t)rowY * 192 + h * 21];
            yr[k15] = f2bf(y0[i] * inv);
            if (k15 < 5) yr[16 + k15] = f2bf(y1[i] * inv);
        }
    } else { // bf16 partials (denominator at d=31)
#pragma unroll
        for (int i = 0; i < 4; i++) {
            size_t pb = (size_t)ci * PART_SLOT +
                        (((size_t)bh << 11) + q0 + w * 16 + g * 4 + i) * 32;
            Part[pb + k15] = f2bf(y0[i]);
            Part[pb + 16 + k15] = f2bf(y1[i]);
        }
    }
}

// combine nc partial slots for rows t >= 512, normalize, write Ybuf. nc = (t>>9)+1.
__global__ __launch_bounds__(256) void attn_reduce(const u16* __restrict__ Part, u16* __restrict__ Ybuf) {
    int gid = blockIdx.x * 256 + threadIdx.x; // 36 * 1536 * 32
    int d = gid & 31;
    int rest = gid >> 5;
    int t = 512 + (rest % 1536);
    int bh = rest / 1536;
    int b = bh / N_HEADS, h = bh - b * N_HEADS;
    int nc = (t >> 9) + 1;
    size_t base = (((size_t)bh << 11) + t) * 32;
    float l = 0.f, v = 0.f;
    for (int ci = 0; ci < nc; ci++) {
        l += bf2f(Part[(size_t)ci * PART_SLOT + base + 31]);
        if (d < 21) v += bf2f(Part[(size_t)ci * PART_SLOT + base + d]);
    }
    if (d < 21) Ybuf[(size_t)(b * T_SEQ + t) * 192 + h * 21 + d] = f2bf(v / l);
}

// ---------------- launch ----------------

extern "C" void kernel_launch(void* const* d_in, const int* in_sizes, int n_in,
                              void* d_out, int out_size, void* d_ws, size_t ws_size,
                              hipStream_t stream) {
    const float* x  = (const float*)d_in[0];
    const float* Wq = (const float*)d_in[1];
    const float* Wk = (const float*)d_in[2];
    const float* Wv = (const float*)d_in[3];
    const float* Wo = (const float*)d_in[4];
    float* out = (float*)d_out;

    char* p = (char*)d_ws;
    auto alloc = [&](size_t bytes) { char* r = p; p += (bytes + 255) & ~(size_t)255; return r; };
    u16*   QpKp   = (u16*)alloc((size_t)ROWS * CDIM * 2);   // Qp | Kp
    u16*   qkv    = (u16*)alloc((size_t)ROWS * CDIM * 2);
    u16*   WcT    = (u16*)alloc((size_t)576 * 576 * 2);
    u16*   WoSubT = (u16*)alloc((size_t)576 * 192 * 2);
    float* cosT   = (float*)alloc((size_t)T_SEQ * 21 * 4);
    float* sinT   = (float*)alloc((size_t)T_SEQ * 21 * 4);
    u16*   Vp     = (u16*)alloc((size_t)NBH * 32 * T_SEQ * 2);
    u16*   Ybuf   = (u16*)alloc((size_t)ROWS * 192 * 2);
    u16*   Part   = (u16*)alloc((size_t)4 * PART_SLOT * 2);

    u16* Qp = QpKp;
    u16* Kp = QpKp + (size_t)NBH * T_SEQ * 32;

    prep_wt<<<dim3((576 * 576 + 255) / 256), dim3(256), 0, stream>>>(Wq, Wk, Wv, Wo, WcT, WoSubT, cosT, sinT);

    // QKV projection: [8192,576(f32)] x [576,567(->576)] — XCD-aligned 1-D grid (64 m x 9 n)
    gemm_mfma<1, 0><<<dim3(64 * 9), dim3(256), 0, stream>>>((const void*)x, WcT, (void*)qkv, 576, 576, 576, 576);

    // merged rope + repack (vectorized loads; Q/K roped rows, V d-major transpose)
    repack_qkv<<<dim3(T_SEQ / 64, NBH), dim3(256), 0, stream>>>(qkv, cosT, sinT, Qp, Kp, Vp);

    // balanced split-K MFMA flash attention (128 q/block, 8 waves) + combine
    attn_mfma<<<dim3(40, NBH), dim3(512), 0, stream>>>(Qp, Kp, Vp, Ybuf, Part);
    attn_reduce<<<dim3(NBH * 1536 * 32 / 256), dim3(256), 0, stream>>>(Part, Ybuf);

    // output GEMM: [8192,192] x [192,576] — XCD-aligned 1-D grid (64 m x 9 n)
    gemm_mfma<0, 1><<<dim3(64 * 9), dim3(256), 0, stream>>>((const void*)Ybuf, WoSubT, (void*)out, 192, 192, 192, 576);
}